// Round 4
// baseline (668.019 us; speedup 1.0000x reference)
//
#include <hip/hip_runtime.h>

// Problem constants (B,T,C,H,E = 8,2048,1024,16,64; TOP_K=38)
#define T_LEN 2048
#define B_DIM 8
#define C_DIM 1024
#define TOPK  38
#define FFT_N 2048

typedef _Float16 half8 __attribute__((ext_vector_type(8)));
typedef float  floatx4 __attribute__((ext_vector_type(4)));
typedef unsigned int u32;

__device__ __forceinline__ void async16(const void* g, void* l) {
  __builtin_amdgcn_global_load_lds(
      (const __attribute__((address_space(1))) u32*)g,
      (__attribute__((address_space(3))) u32*)l, 16, 0, 0);
}

__device__ __forceinline__ int rev11(int x) { return (int)(__brev((u32)x) >> 21); }

// ---------------------------------------------------------------- zero fill
__global__ __launch_bounds__(256) void zero_kernel(float* __restrict__ p, int n) {
  int i = blockIdx.x * 256 + threadIdx.x;
  if (i < n) p[i] = 0.0f;
}

// ---------------------------------------------------------------- f32 -> fp16 (8/thread)
__global__ __launch_bounds__(256) void cvt_f16_kernel(
    const float* __restrict__ src, _Float16* __restrict__ dst, int n8) {
  int i = blockIdx.x * 256 + threadIdx.x;
  if (i >= n8) return;
  floatx4 a = ((const floatx4*)src)[i * 2];
  floatx4 b = ((const floatx4*)src)[i * 2 + 1];
  half8 o;
  #pragma unroll
  for (int j = 0; j < 4; ++j) { o[j] = (_Float16)a[j]; o[j + 4] = (_Float16)b[j]; }
  ((half8*)dst)[i] = o;
}

// ---------------------------------------------------------------- W [K,N] f32 -> Wt [N,K] fp16 (batched x3)
__global__ __launch_bounds__(256) void wt3_kernel(
    const float* __restrict__ w0, const float* __restrict__ w1,
    const float* __restrict__ w2, _Float16* __restrict__ d0,
    _Float16* __restrict__ d1, _Float16* __restrict__ d2) {
  const float* src = blockIdx.z == 0 ? w0 : (blockIdx.z == 1 ? w1 : w2);
  _Float16*    dst = blockIdx.z == 0 ? d0 : (blockIdx.z == 1 ? d1 : d2);
  __shared__ _Float16 tile[64][65];
  int k0 = blockIdx.y * 64, n0 = blockIdx.x * 64;
  int tx = threadIdx.x & 63, ty = threadIdx.x >> 6;  // ty 0..3
  #pragma unroll
  for (int j = 0; j < 16; ++j) {
    int r = j * 4 + ty;
    tile[r][tx] = (_Float16)src[(size_t)(k0 + r) * C_DIM + n0 + tx];
  }
  __syncthreads();
  #pragma unroll
  for (int j = 0; j < 16; ++j) {
    int r = j * 4 + ty;
    dst[(size_t)(n0 + r) * C_DIM + k0 + tx] = tile[tx][r];
  }
}

// ---------------------------------------------------------------- fp16 [B][T][C] -> [B][C][T] transpose
__global__ __launch_bounds__(256) void tr16_kernel(
    const _Float16* __restrict__ src, _Float16* __restrict__ dst) {
  __shared__ _Float16 tile[64][65];
  int b = blockIdx.z;
  int t0 = blockIdx.x * 64, c0 = blockIdx.y * 64;
  const _Float16* s = src + (size_t)b * T_LEN * C_DIM;
  _Float16* d = dst + (size_t)b * C_DIM * T_LEN;
  int tid = threadIdx.x;
  int c8 = (tid & 7) * 8, tr = tid >> 3;          // tr 0..31
  #pragma unroll
  for (int h = 0; h < 2; ++h) {
    int r = tr + h * 32;
    half8 v = *(const half8*)&s[(size_t)(t0 + r) * C_DIM + c0 + c8];
    #pragma unroll
    for (int j = 0; j < 8; ++j) tile[r][c8 + j] = v[j];
  }
  __syncthreads();
  int t8 = (tid & 7) * 8, cr = tid >> 3;
  #pragma unroll
  for (int h = 0; h < 2; ++h) {
    int c = cr + h * 32;
    half8 o;
    #pragma unroll
    for (int j = 0; j < 8; ++j) o[j] = tile[t8 + j][c];
    *(half8*)&d[(size_t)(c0 + c) * T_LEN + t0 + t8] = o;
  }
}

// ---------------------------------------------------------------- twiddles tw[k] = exp(-i*pi*k/1024), k<1024
__global__ __launch_bounds__(256) void twiddle_kernel(float* __restrict__ twg) {
  int k = blockIdx.x * 256 + threadIdx.x;
  if (k < FFT_N / 2) {
    float th = -3.14159265358979323846f * (float)k / 1024.0f;
    twg[2 * k]     = cosf(th);
    twg[2 * k + 1] = sinf(th);
  }
}

// ---------------------------------------------------------------- per-channel FFT cross-spectrum
// z_c = XMt[b][c][:] + i*Xt[b][c][:]; Zf via in-place radix-2 DIF (bit-rev output).
// Separation: XMf[k]=(Z[k]+conj(Z[N-k]))/2, Xf[k]=(Z[k]-conj(Z[N-k]))/(2i);
// P[k]=XMf[k]*conj(Xf[k]); acc[k]+=P, acc[N-k]+=conj(P) (natural order).
// Butterfly pairs are a disjoint partition of 0..N-1 per stage -> barrier per
// stage suffices (no cross-lane RMW aliasing; round-1 lesson does not apply).
#define CG 16
__global__ __launch_bounds__(256) void fft_corr_kernel(
    const _Float16* __restrict__ XMt, const _Float16* __restrict__ Xt,
    const float* __restrict__ twg, float* __restrict__ spec) {
  __shared__ float re[FFT_N], im[FFT_N];
  __shared__ float accr[FFT_N], acci[FFT_N];
  __shared__ float twr[FFT_N / 2], twi[FFT_N / 2];
  const int tid = threadIdx.x;
  const int b = blockIdx.x >> 6;                 // 64 blocks per batch
  const int cg0 = (blockIdx.x & 63) * CG;
  for (int i = tid; i < FFT_N / 2; i += 256) { twr[i] = twg[2 * i]; twi[i] = twg[2 * i + 1]; }
  for (int i = tid; i < FFT_N; i += 256) { accr[i] = 0.0f; acci[i] = 0.0f; }
  const _Float16* xmB = XMt + (size_t)b * C_DIM * T_LEN;
  const _Float16* xB  = Xt  + (size_t)b * C_DIM * T_LEN;
  __syncthreads();
  for (int cc = 0; cc < CG; ++cc) {
    const int c = cg0 + cc;
    const half8* pm = (const half8*)(xmB + (size_t)c * T_LEN);
    const half8* px = (const half8*)(xB  + (size_t)c * T_LEN);
    for (int i = tid; i < FFT_N / 8; i += 256) {
      half8 a = pm[i]; half8 bb = px[i];
      #pragma unroll
      for (int j = 0; j < 8; ++j) { re[i * 8 + j] = (float)a[j]; im[i * 8 + j] = (float)bb[j]; }
    }
    __syncthreads();
    #pragma unroll 1
    for (int s = 0; s < 11; ++s) {
      const int half = 1024 >> s, tstep = 1 << s;
      #pragma unroll
      for (int r = 0; r < 4; ++r) {
        int idx = tid + r * 256;
        int j = idx & (half - 1);
        int i0 = 2 * idx - j, i1 = i0 + half;
        float ur = re[i0], ui = im[i0], vr = re[i1], vi = im[i1];
        float sr = ur - vr, si = ui - vi;
        float wr = twr[j * tstep], wi = twi[j * tstep];
        re[i0] = ur + vr; im[i0] = ui + vi;
        re[i1] = sr * wr - si * wi;
        im[i1] = sr * wi + si * wr;
      }
      __syncthreads();
    }
    // separation + accumulate (each acc index written by exactly one thread)
    for (int k = tid; k < FFT_N / 2; k += 256) {
      if (k == 0) {
        accr[0]    += re[0] * im[0];               // Z[0] at pos 0
        accr[1024] += re[1] * im[1];               // Z[1024] at pos rev(1024)=1
      } else {
        int pk = rev11(k), pn = rev11(FFT_N - k);
        float zr = re[pk], zi = im[pk], yr = re[pn], yi = im[pn];
        float ar = 0.5f * (zr + yr), ai = 0.5f * (zi - yi);   // XMf[k]
        float br = 0.5f * (zi + yi), bi = -0.5f * (zr - yr);  // Xf[k]
        float pr = ar * br + ai * bi, pi = ai * br - ar * bi; // XMf*conj(Xf)
        accr[k] += pr;          acci[k] += pi;
        accr[FFT_N - k] += pr;  acci[FFT_N - k] -= pi;
      }
    }
    __syncthreads();
  }
  float* sb = spec + (size_t)b * FFT_N * 2;
  for (int i = tid; i < FFT_N; i += 256) {
    atomicAdd(&sb[2 * i],     accr[i]);
    atomicAdd(&sb[2 * i + 1], acci[i]);
  }
}

// ---------------------------------------------------------------- inverse FFT + top-k + softmax
// Conj-twiddle DIF on the natural-order spectrum = N*IDFT, bit-rev output;
// vals[rev(p)] = re[p] / (2048*1024)  == reference mean_value.
__global__ __launch_bounds__(256) void ifft_topk_kernel(
    const float* __restrict__ spec, const float* __restrict__ twg,
    float* __restrict__ wgt, int* __restrict__ dly) {
  __shared__ float re[FFT_N], im[FFT_N];
  __shared__ float twr[FFT_N / 2], twi[FFT_N / 2];
  __shared__ float vals[FFT_N];
  __shared__ float swv[4];
  __shared__ int   swidx[4];
  __shared__ float selw[TOPK];
  __shared__ int   seli[TOPK];
  int b = blockIdx.x, tid = threadIdx.x;
  for (int i = tid; i < FFT_N / 2; i += 256) { twr[i] = twg[2 * i]; twi[i] = twg[2 * i + 1]; }
  const float* sb = spec + (size_t)b * FFT_N * 2;
  for (int i = tid; i < FFT_N; i += 256) { re[i] = sb[2 * i]; im[i] = sb[2 * i + 1]; }
  __syncthreads();
  #pragma unroll 1
  for (int s = 0; s < 11; ++s) {
    const int half = 1024 >> s, tstep = 1 << s;
    #pragma unroll
    for (int r = 0; r < 4; ++r) {
      int idx = tid + r * 256;
      int j = idx & (half - 1);
      int i0 = 2 * idx - j, i1 = i0 + half;
      float ur = re[i0], ui = im[i0], vr = re[i1], vi = im[i1];
      float sr = ur - vr, si = ui - vi;
      float wr = twr[j * tstep], wi = twi[j * tstep];
      re[i0] = ur + vr; im[i0] = ui + vi;
      re[i1] = sr * wr + si * wi;          // (sr+i si)*conj(w)
      im[i1] = si * wr - sr * wi;
    }
    __syncthreads();
  }
  const float sc = 1.0f / 2097152.0f;      // 1/2048 (IDFT) * 1/1024 (channel mean)
  for (int i = tid; i < FFT_N; i += 256) vals[rev11(i)] = re[i] * sc;
  __syncthreads();
  for (int it = 0; it < TOPK; ++it) {
    float bv = -3.4e38f; int bi = T_LEN - 1;
    for (int i = tid; i < T_LEN; i += 256) {
      float v = vals[i];
      if (v > bv || (v == bv && i < bi)) { bv = v; bi = i; }
    }
    #pragma unroll
    for (int off = 32; off > 0; off >>= 1) {
      float ov = __shfl_down(bv, off);
      int   oi = __shfl_down(bi, off);
      if (ov > bv || (ov == bv && oi < bi)) { bv = ov; bi = oi; }
    }
    if ((tid & 63) == 0) { swv[tid >> 6] = bv; swidx[tid >> 6] = bi; }
    __syncthreads();
    if (tid == 0) {
      #pragma unroll
      for (int ww = 1; ww < 4; ++ww) {
        float ov = swv[ww]; int oi = swidx[ww];
        if (ov > bv || (ov == bv && oi < bi)) { bv = ov; bi = oi; }
      }
      if (bi < 0) bi = 0; if (bi > T_LEN - 1) bi = T_LEN - 1;
      selw[it] = bv; seli[it] = bi;
      vals[bi] = -3.4e38f;
    }
    __syncthreads();
  }
  if (tid == 0) {
    float m = selw[0], s = 0.0f, e[TOPK];
    for (int i = 0; i < TOPK; ++i) { e[i] = expf(selw[i] - m); s += e[i]; }
    float inv = 1.0f / s;
    for (int i = 0; i < TOPK; ++i) { wgt[b * TOPK + i] = e[i] * inv; dly[b * TOPK + i] = seli[i]; }
  }
}

// ---------------------------------------------------------------- fp16 NT GEMM (m97-style + read swizzle)
// C[m,n] = sum_k A[m*K+k]*B[n*K+k]; EPI: 0 = fp16 store + bias, 1 = f32 store + bias.
// Source-chunk swizzle chunk' = chunk ^ (row&7) keeps LDS dest linear (rule 21)
// and makes fragment reads 2-way max (conflicts measured 0 in round 3).
template <int EPI>
__global__ __launch_bounds__(256, 3) void gemm_f16_kernel(
    const _Float16* __restrict__ A, const _Float16* __restrict__ B,
    const float* __restrict__ bias, void* __restrict__ outv, int N, int K) {
  __shared__ __align__(16) _Float16 lA[128 * 64];
  __shared__ __align__(16) _Float16 lB[128 * 64];

  const int tid = threadIdx.x;
  const int bm = blockIdx.x, bn = blockIdx.y;
  const int lane = tid & 63, w = tid >> 6;
  const int wm = w >> 1, wn = w & 1;     // 2x2 waves -> 64x64 tiles
  const int lr = lane & 15, lg = lane >> 4;

  const int lrow = lane >> 3;            // 0..7 = row within 8-row slab
  const int lcol = (((lane & 7) ^ lrow) * 8);

  const _Float16* pA[4];
  const _Float16* pB[4];
  _Float16* dA[4];
  _Float16* dB[4];
  #pragma unroll
  for (int j = 0; j < 4; ++j) {
    int r = w * 32 + j * 8;
    pA[j] = A + (long long)(bm * 128 + r + lrow) * K + lcol;
    pB[j] = B + (long long)(bn * 128 + r + lrow) * K + lcol;
    dA[j] = &lA[r * 64];
    dB[j] = &lB[r * 64];
  }

  const int coff = (((lr >> 2) & 1) * 32) | ((lg ^ (lr & 3)) * 8);

  floatx4 acc[4][4];
  #pragma unroll
  for (int i = 0; i < 4; ++i)
    #pragma unroll
    for (int j = 0; j < 4; ++j) { acc[i][j][0]=0.f; acc[i][j][1]=0.f; acc[i][j][2]=0.f; acc[i][j][3]=0.f; }

  const int nk = K >> 6;
  for (int kt = 0; kt < nk; ++kt) {
    __syncthreads();
    #pragma unroll
    for (int j = 0; j < 4; ++j) {
      async16(pA[j], dA[j]);
      async16(pB[j], dB[j]);
      pA[j] += 64; pB[j] += 64;
    }
    __syncthreads();
    #pragma unroll
    for (int s = 0; s < 2; ++s) {
      const int so = coff ^ (s * 32);
      half8 af[4], bf[4];
      #pragma unroll
      for (int mi = 0; mi < 4; ++mi)
        af[mi] = *(const half8*)&lA[(wm * 64 + mi * 16 + lr) * 64 + so];
      #pragma unroll
      for (int ni = 0; ni < 4; ++ni)
        bf[ni] = *(const half8*)&lB[(wn * 64 + ni * 16 + lr) * 64 + so];
      #pragma unroll
      for (int mi = 0; mi < 4; ++mi)
        #pragma unroll
        for (int ni = 0; ni < 4; ++ni)
          acc[mi][ni] = __builtin_amdgcn_mfma_f32_16x16x32_f16(
              af[mi], bf[ni], acc[mi][ni], 0, 0, 0);
    }
  }

  float bvs[4];
  #pragma unroll
  for (int ni = 0; ni < 4; ++ni) {
    int gc = bn * 128 + wn * 64 + ni * 16 + lr;
    bvs[ni] = bias ? bias[gc & (C_DIM - 1)] : 0.0f;
  }
  #pragma unroll
  for (int mi = 0; mi < 4; ++mi)
    #pragma unroll
    for (int ni = 0; ni < 4; ++ni) {
      int gc = bn * 128 + wn * 64 + ni * 16 + lr;
      #pragma unroll
      for (int i = 0; i < 4; ++i) {
        int gr = bm * 128 + wm * 64 + mi * 16 + lg * 4 + i;
        float v = acc[mi][ni][i] + bvs[ni];
        long long idx = (long long)gr * N + gc;
        if constexpr (EPI == 1) ((float*)outv)[idx] = v;
        else                    ((_Float16*)outv)[idx] = (_Float16)v;
      }
    }
}

// ---------------------------------------------------------------- aggregation (+reference's reshape)
__global__ __launch_bounds__(256) void aggregate_kernel(
    const _Float16* __restrict__ V, const float* __restrict__ wgt,
    const int* __restrict__ dly, _Float16* __restrict__ V2) {
  int b = blockIdx.x & 7;                         // batch pinned to XCD
  int g = (blockIdx.x >> 3) * 256 + threadIdx.x;  // 0 .. T*C/8-1
  int c8 = g & 127;
  int tp = g >> 7;
  int h = tp >> 7, lhi = tp & 127;
  int cp = c8 << 3;
  int e0 = cp & 63, lo = cp >> 6;
  int l = lhi * 16 + lo;
  int ch = h * 64 + e0;
  float acc[8];
  #pragma unroll
  for (int j = 0; j < 8; ++j) acc[j] = 0.0f;
  const long long vbase = (long long)b * T_LEN * C_DIM;
  for (int k = 0; k < TOPK; ++k) {
    float w = wgt[b * TOPK + k];
    int d = dly[b * TOPK + k];
    int ts = (l + d) & (T_LEN - 1);
    half8 vv = *(const half8*)(V + vbase + (long long)ts * C_DIM + ch);
    #pragma unroll
    for (int j = 0; j < 8; ++j) acc[j] += w * (float)vv[j];
  }
  half8 o;
  #pragma unroll
  for (int j = 0; j < 8; ++j) o[j] = (_Float16)acc[j];
  __builtin_nontemporal_store(o, (half8*)(V2 + vbase + (long long)tp * C_DIM + cp));
}

// ---------------------------------------------------------------- launcher
extern "C" void kernel_launch(void* const* d_in, const int* in_sizes, int n_in,
                              void* d_out, int out_size, void* d_ws, size_t ws_size,
                              hipStream_t stream) {
  const float* x  = (const float*)d_in[0];
  const float* Wq = (const float*)d_in[1];
  const float* Wk = (const float*)d_in[3];
  const float* Wv = (const float*)d_in[5];
  const float* bv = (const float*)d_in[6];
  const float* Wp = (const float*)d_in[7];
  const float* bp = (const float*)d_in[8];
  // bq/bk provably irrelevant (constant shift of corr; top-k order & softmax shift-invariant)

  // corr path: Q.K^T == X (Wq Wk^T) X^T; corr[l] = sum_c circcorr(XM_c, x_c)[l]
  //            computed in O(N log N) per channel via FFT cross-spectrum.
  // d_out (64 MiB):
  //   [0,32M)  xh fp16 (live until Xt transpose) -> then spec(128K)+twg(8K)
  //   [32,64M) Wqh/Wkh/Wvt/Mt2 (2M each, dead after XM & V GEMMs) -> then XMt (32M)
  // ws (>= 64MiB + 72KiB proven):
  //   [0,32M)  XMh -> Xt -> V2      [32,64M) V -> Wpt      tail: wgt, dly
  const size_t SZ_H = (size_t)B_DIM * T_LEN * C_DIM * 2;   // 32 MiB
  const size_t NEEDED = 2 * SZ_H + 65536 + 8192;
  if (ws_size < NEEDED) return;

  char* ws = (char*)d_ws;
  _Float16* XMh = (_Float16*)ws;
  _Float16* V   = (_Float16*)(ws + SZ_H);
  float* wgt   = (float*)(ws + 2 * SZ_H + 65536);
  int*   dly   = (int*)(ws + 2 * SZ_H + 65536 + 4096);
  _Float16* Xt  = (_Float16*)ws;             // after XM transpose (XMh dead)
  _Float16* V2  = (_Float16*)ws;             // after fft_corr (Xt dead)
  _Float16* Wpt = (_Float16*)(ws + SZ_H);    // after agg (V dead), 2 MiB

  char* dob = (char*)d_out;
  _Float16* xh  = (_Float16*)dob;
  float*    spec = (float*)dob;                        // after xh dead: 128 KiB
  float*    twg  = (float*)(dob + 131072);             // 8 KiB
  _Float16* Wqh = (_Float16*)(dob + 32 * 1048576);
  _Float16* Wkh = (_Float16*)(dob + 34 * 1048576);
  _Float16* Wvt = (_Float16*)(dob + 36 * 1048576);
  _Float16* Mt2 = (_Float16*)(dob + 38 * 1048576);
  _Float16* XMt = (_Float16*)(dob + 32 * 1048576);     // after weights dead: 32 MiB

  const int M = B_DIM * T_LEN;  // 16384

  cvt_f16_kernel<<<(M * C_DIM / 8) / 256, 256, 0, stream>>>(x, xh, M * C_DIM / 8);
  cvt_f16_kernel<<<(C_DIM * C_DIM / 8) / 256, 256, 0, stream>>>(Wq, Wqh, C_DIM * C_DIM / 8);
  cvt_f16_kernel<<<(C_DIM * C_DIM / 8) / 256, 256, 0, stream>>>(Wk, Wkh, C_DIM * C_DIM / 8);

  dim3 tgrid(16, 16, 1);
  wt3_kernel<<<tgrid, 256, 0, stream>>>(Wv, Wv, Wv, Wvt, Wvt, Wvt);   // z=0 slice only

  dim3 pgrid(M / 128, C_DIM / 128, 1);        // (128, 8)
  dim3 mgrid(C_DIM / 128, C_DIM / 128, 1);    // (8, 8)

  // Mt2[m,n] = sum_o Wk[m,o] * Wq[n,o]
  gemm_f16_kernel<0><<<mgrid, 256, 0, stream>>>(Wkh, Wqh, nullptr, Mt2, C_DIM, C_DIM);
  // XM[t,c] = sum_a x[t,a] * Mt2[c,a] = sum_o Q[t,o] Wk[c,o]
  gemm_f16_kernel<0><<<pgrid, 256, 0, stream>>>(xh, Mt2, nullptr, XMh, C_DIM, C_DIM);
  // V = xh @ Wvt + bv   (before transposes so Wvt dies before XMt overlays it)
  gemm_f16_kernel<0><<<pgrid, 256, 0, stream>>>(xh, Wvt, bv, V, C_DIM, C_DIM);

  dim3 trgrid(T_LEN / 64, C_DIM / 64, B_DIM); // (32, 16, 8)
  tr16_kernel<<<trgrid, 256, 0, stream>>>(XMh, XMt);   // XMh dead after
  tr16_kernel<<<trgrid, 256, 0, stream>>>(xh, Xt);     // xh dead after

  zero_kernel<<<(B_DIM * FFT_N * 2) / 256, 256, 0, stream>>>(spec, B_DIM * FFT_N * 2);
  twiddle_kernel<<<4, 256, 0, stream>>>(twg);

  fft_corr_kernel<<<B_DIM * (C_DIM / CG), 256, 0, stream>>>(XMt, Xt, twg, spec);
  ifft_topk_kernel<<<B_DIM, 256, 0, stream>>>(spec, twg, wgt, dly);

  aggregate_kernel<<<(T_LEN * C_DIM / 8 / 256) * B_DIM, 256, 0, stream>>>(V, wgt, dly, V2);

  wt3_kernel<<<tgrid, 256, 0, stream>>>(Wp, Wp, Wp, Wpt, Wpt, Wpt);  // z=0 slice only

  // out = V2 @ Wpt + bp -> d_out f32 (spec/twg/XMt dead)
  gemm_f16_kernel<1><<<pgrid, 256, 0, stream>>>(V2, Wpt, bp, d_out, C_DIM, C_DIM);
}

// Round 5
// 529.100 us; speedup vs baseline: 1.2626x; 1.2626x over previous
//
#include <hip/hip_runtime.h>

// Problem constants (B,T,C,H,E = 8,2048,1024,16,64; TOP_K=38)
#define T_LEN 2048
#define B_DIM 8
#define C_DIM 1024
#define TOPK  38
#define FFT_N 2048
#define SPEC_ST 2050   // floats per batch: 1025 complex (k=0..1024)

typedef _Float16 half8 __attribute__((ext_vector_type(8)));
typedef float  floatx4 __attribute__((ext_vector_type(4)));
typedef unsigned int u32;

__device__ __forceinline__ void async16(const void* g, void* l) {
  __builtin_amdgcn_global_load_lds(
      (const __attribute__((address_space(1))) u32*)g,
      (__attribute__((address_space(3))) u32*)l, 16, 0, 0);
}

__device__ __forceinline__ int rev11(int x) { return (int)(__brev((u32)x) >> 21); }
// LDS bank swizzle: XOR high addr bits into bank field. Bijective (triangular).
// Makes (a) stride-8 scatter, (b) bit-reversed access, (c) stride-2^s twiddle
// reads all <=4-way instead of 16..64-way.
__device__ __forceinline__ int SW(int a) { return a ^ ((a >> 5) & 31); }

// ---------------------------------------------------------------- zero fill
__global__ __launch_bounds__(256) void zero_kernel(float* __restrict__ p, int n) {
  int i = blockIdx.x * 256 + threadIdx.x;
  if (i < n) p[i] = 0.0f;
}

// ---------------------------------------------------------------- f32 -> fp16 (8/thread)
__global__ __launch_bounds__(256) void cvt_f16_kernel(
    const float* __restrict__ src, _Float16* __restrict__ dst, int n8) {
  int i = blockIdx.x * 256 + threadIdx.x;
  if (i >= n8) return;
  floatx4 a = ((const floatx4*)src)[i * 2];
  floatx4 b = ((const floatx4*)src)[i * 2 + 1];
  half8 o;
  #pragma unroll
  for (int j = 0; j < 4; ++j) { o[j] = (_Float16)a[j]; o[j + 4] = (_Float16)b[j]; }
  ((half8*)dst)[i] = o;
}

// ---------------------------------------------------------------- W [K,N] f32 -> Wt [N,K] fp16 (batched x3)
__global__ __launch_bounds__(256) void wt3_kernel(
    const float* __restrict__ w0, const float* __restrict__ w1,
    const float* __restrict__ w2, _Float16* __restrict__ d0,
    _Float16* __restrict__ d1, _Float16* __restrict__ d2) {
  const float* src = blockIdx.z == 0 ? w0 : (blockIdx.z == 1 ? w1 : w2);
  _Float16*    dst = blockIdx.z == 0 ? d0 : (blockIdx.z == 1 ? d1 : d2);
  __shared__ _Float16 tile[64][65];
  int k0 = blockIdx.y * 64, n0 = blockIdx.x * 64;
  int tx = threadIdx.x & 63, ty = threadIdx.x >> 6;  // ty 0..3
  #pragma unroll
  for (int j = 0; j < 16; ++j) {
    int r = j * 4 + ty;
    tile[r][tx] = (_Float16)src[(size_t)(k0 + r) * C_DIM + n0 + tx];
  }
  __syncthreads();
  #pragma unroll
  for (int j = 0; j < 16; ++j) {
    int r = j * 4 + ty;
    dst[(size_t)(n0 + r) * C_DIM + k0 + tx] = tile[tx][r];
  }
}

// ---------------------------------------------------------------- fp16 [B][T][C] -> [B][C][T] transpose
__global__ __launch_bounds__(256) void tr16_kernel(
    const _Float16* __restrict__ src, _Float16* __restrict__ dst) {
  __shared__ _Float16 tile[64][65];
  int b = blockIdx.z;
  int t0 = blockIdx.x * 64, c0 = blockIdx.y * 64;
  const _Float16* s = src + (size_t)b * T_LEN * C_DIM;
  _Float16* d = dst + (size_t)b * C_DIM * T_LEN;
  int tid = threadIdx.x;
  int c8 = (tid & 7) * 8, tr = tid >> 3;          // tr 0..31
  #pragma unroll
  for (int h = 0; h < 2; ++h) {
    int r = tr + h * 32;
    half8 v = *(const half8*)&s[(size_t)(t0 + r) * C_DIM + c0 + c8];
    #pragma unroll
    for (int j = 0; j < 8; ++j) tile[r][c8 + j] = v[j];
  }
  __syncthreads();
  int t8 = (tid & 7) * 8, cr = tid >> 3;
  #pragma unroll
  for (int h = 0; h < 2; ++h) {
    int c = cr + h * 32;
    half8 o;
    #pragma unroll
    for (int j = 0; j < 8; ++j) o[j] = tile[t8 + j][c];
    *(half8*)&d[(size_t)(c0 + c) * T_LEN + t0 + t8] = o;
  }
}

// ---------------------------------------------------------------- twiddles tw[k] = exp(-i*pi*k/1024), k<1024
__global__ __launch_bounds__(256) void twiddle_kernel(float* __restrict__ twg) {
  int k = blockIdx.x * 256 + threadIdx.x;
  if (k < FFT_N / 2) {
    float th = -3.14159265358979323846f * (float)k / 1024.0f;
    twg[2 * k]     = cosf(th);
    twg[2 * k + 1] = sinf(th);
  }
}

// ---------------------------------------------------------------- per-channel FFT cross-spectrum
// z_c = XMt[b][c][:] + i*Xt[b][c][:]; Zf via in-place radix-2 DIF (bit-rev output,
// all LDS indices SW-swizzled). Separation (k=1..1023):
//   XMf[k]=(Z[k]+conj(Z[N-k]))/2, Xf[k]=(Z[k]-conj(Z[N-k]))/(2i),
//   S[k]=XMf[k]*conj(Xf[k]) accumulated in REGISTERS (thread owns k=tid+256r),
// then one global atomicAdd per (k<=1024) at block end. S[N-k]=conj(S[k]) is
// reconstructed at IFFT load (not stored).
#define CG 8
__global__ __launch_bounds__(256) void fft_corr_kernel(
    const _Float16* __restrict__ XMt, const _Float16* __restrict__ Xt,
    const float* __restrict__ twg, float* __restrict__ spec) {
  __shared__ float re[FFT_N], im[FFT_N];
  __shared__ float twr[FFT_N / 2], twi[FFT_N / 2];
  const int tid = threadIdx.x;
  const int b = blockIdx.x >> 7;                 // 128 blocks per batch
  const int cg0 = (blockIdx.x & 127) * CG;
  for (int i = tid; i < FFT_N / 2; i += 256) { twr[SW(i)] = twg[2 * i]; twi[SW(i)] = twg[2 * i + 1]; }
  const _Float16* xmB = XMt + (size_t)b * C_DIM * T_LEN;
  const _Float16* xB  = Xt  + (size_t)b * C_DIM * T_LEN;
  float sR[4] = {0.f, 0.f, 0.f, 0.f};
  float sI[4] = {0.f, 0.f, 0.f, 0.f};
  float s1024 = 0.f;
  __syncthreads();
  for (int cc = 0; cc < CG; ++cc) {
    const int c = cg0 + cc;
    const half8* pm = (const half8*)(xmB + (size_t)c * T_LEN);
    const half8* px = (const half8*)(xB  + (size_t)c * T_LEN);
    for (int i = tid; i < FFT_N / 8; i += 256) {
      half8 a = pm[i]; half8 bb = px[i];
      #pragma unroll
      for (int j = 0; j < 8; ++j) {
        re[SW(i * 8 + j)] = (float)a[j];
        im[SW(i * 8 + j)] = (float)bb[j];
      }
    }
    __syncthreads();
    #pragma unroll 1
    for (int s = 0; s < 11; ++s) {
      const int half = 1024 >> s, tstep = 1 << s;
      #pragma unroll
      for (int r = 0; r < 4; ++r) {
        int idx = tid + r * 256;
        int j = idx & (half - 1);
        int i0 = SW(2 * idx - j), i1 = SW(2 * idx - j + half);
        float ur = re[i0], ui = im[i0], vr = re[i1], vi = im[i1];
        float sr = ur - vr, si = ui - vi;
        int tix = SW(j * tstep);
        float wr = twr[tix], wi = twi[tix];
        re[i0] = ur + vr; im[i0] = ui + vi;
        re[i1] = sr * wr - si * wi;
        im[i1] = sr * wi + si * wr;
      }
      __syncthreads();
    }
    // separation + register accumulation (k = tid + 256r, k <= 1023)
    #pragma unroll
    for (int r = 0; r < 4; ++r) {
      int k = tid + r * 256;
      if (k == 0) {
        sR[0]  += re[0] * im[0];                  // S[0]    (Z[0] at pos 0)
        s1024  += re[1] * im[1];                  // S[1024] (Z[1024] at pos rev=1)
      } else {
        int pk = SW(rev11(k)), pn = SW(rev11(FFT_N - k));
        float zr = re[pk], zi = im[pk], yr = re[pn], yi = im[pn];
        float ar = 0.5f * (zr + yr), ai = 0.5f * (zi - yi);   // XMf[k]
        float br = 0.5f * (zi + yi), bi = -0.5f * (zr - yr);  // Xf[k]
        sR[r] += ar * br + ai * bi;               // Re(XMf*conj(Xf))
        sI[r] += ai * br - ar * bi;               // Im
      }
    }
    __syncthreads();                              // protect re/im vs next load
  }
  float* sb = spec + (size_t)b * SPEC_ST;
  #pragma unroll
  for (int r = 0; r < 4; ++r) {
    int k = tid + r * 256;
    atomicAdd(&sb[2 * k],     sR[r]);
    atomicAdd(&sb[2 * k + 1], sI[r]);
  }
  if (tid == 0) atomicAdd(&sb[2048], s1024);
}

// ---------------------------------------------------------------- inverse FFT + top-k + softmax
// Load k=0..1024, Hermitian-mirror to 1025..2047; conj-twiddle DIF (= N*IDFT,
// bit-rev output); vals[rev(p)] = re[p]/(2048*1024) == reference mean_value.
__global__ __launch_bounds__(256) void ifft_topk_kernel(
    const float* __restrict__ spec, const float* __restrict__ twg,
    float* __restrict__ wgt, int* __restrict__ dly) {
  __shared__ float re[FFT_N], im[FFT_N];
  __shared__ float twr[FFT_N / 2], twi[FFT_N / 2];
  __shared__ float vals[FFT_N];
  __shared__ float swv[4];
  __shared__ int   swidx[4];
  __shared__ float selw[TOPK];
  __shared__ int   seli[TOPK];
  int b = blockIdx.x, tid = threadIdx.x;
  for (int i = tid; i < FFT_N / 2; i += 256) { twr[SW(i)] = twg[2 * i]; twi[SW(i)] = twg[2 * i + 1]; }
  const float* sb = spec + (size_t)b * SPEC_ST;
  for (int i = tid; i < FFT_N; i += 256) {
    int src = (i <= 1024) ? i : (FFT_N - i);
    float sgn = (i <= 1024) ? 1.0f : -1.0f;
    re[SW(i)] = sb[2 * src];
    im[SW(i)] = sgn * sb[2 * src + 1];
  }
  __syncthreads();
  #pragma unroll 1
  for (int s = 0; s < 11; ++s) {
    const int half = 1024 >> s, tstep = 1 << s;
    #pragma unroll
    for (int r = 0; r < 4; ++r) {
      int idx = tid + r * 256;
      int j = idx & (half - 1);
      int i0 = SW(2 * idx - j), i1 = SW(2 * idx - j + half);
      float ur = re[i0], ui = im[i0], vr = re[i1], vi = im[i1];
      float sr = ur - vr, si = ui - vi;
      int tix = SW(j * tstep);
      float wr = twr[tix], wi = twi[tix];
      re[i0] = ur + vr; im[i0] = ui + vi;
      re[i1] = sr * wr + si * wi;          // (sr+i si)*conj(w)
      im[i1] = si * wr - sr * wi;
    }
    __syncthreads();
  }
  const float sc = 1.0f / 2097152.0f;      // 1/2048 (IDFT) * 1/1024 (channel mean)
  for (int i = tid; i < FFT_N; i += 256) vals[SW(rev11(i))] = re[SW(i)] * sc;
  __syncthreads();
  for (int it = 0; it < TOPK; ++it) {
    float bv = -3.4e38f; int bi = T_LEN - 1;
    for (int i = tid; i < T_LEN; i += 256) {
      float v = vals[SW(i)];
      if (v > bv || (v == bv && i < bi)) { bv = v; bi = i; }
    }
    #pragma unroll
    for (int off = 32; off > 0; off >>= 1) {
      float ov = __shfl_down(bv, off);
      int   oi = __shfl_down(bi, off);
      if (ov > bv || (ov == bv && oi < bi)) { bv = ov; bi = oi; }
    }
    if ((tid & 63) == 0) { swv[tid >> 6] = bv; swidx[tid >> 6] = bi; }
    __syncthreads();
    if (tid == 0) {
      #pragma unroll
      for (int ww = 1; ww < 4; ++ww) {
        float ov = swv[ww]; int oi = swidx[ww];
        if (ov > bv || (ov == bv && oi < bi)) { bv = ov; bi = oi; }
      }
      if (bi < 0) bi = 0; if (bi > T_LEN - 1) bi = T_LEN - 1;
      selw[it] = bv; seli[it] = bi;
      vals[SW(bi)] = -3.4e38f;
    }
    __syncthreads();
  }
  if (tid == 0) {
    float m = selw[0], s = 0.0f, e[TOPK];
    for (int i = 0; i < TOPK; ++i) { e[i] = expf(selw[i] - m); s += e[i]; }
    float inv = 1.0f / s;
    for (int i = 0; i < TOPK; ++i) { wgt[b * TOPK + i] = e[i] * inv; dly[b * TOPK + i] = seli[i]; }
  }
}

// ---------------------------------------------------------------- fp16 NT GEMM (m97-style + read swizzle)
// C[m,n] = sum_k A[m*K+k]*B[n*K+k]; EPI: 0 = fp16 store + bias, 1 = f32 store + bias.
// Source-chunk swizzle chunk' = chunk ^ (row&7) keeps LDS dest linear (rule 21)
// and makes fragment reads 2-way max (conflicts measured 0 in round 3).
template <int EPI>
__global__ __launch_bounds__(256, 3) void gemm_f16_kernel(
    const _Float16* __restrict__ A, const _Float16* __restrict__ B,
    const float* __restrict__ bias, void* __restrict__ outv, int N, int K) {
  __shared__ __align__(16) _Float16 lA[128 * 64];
  __shared__ __align__(16) _Float16 lB[128 * 64];

  const int tid = threadIdx.x;
  const int bm = blockIdx.x, bn = blockIdx.y;
  const int lane = tid & 63, w = tid >> 6;
  const int wm = w >> 1, wn = w & 1;     // 2x2 waves -> 64x64 tiles
  const int lr = lane & 15, lg = lane >> 4;

  const int lrow = lane >> 3;            // 0..7 = row within 8-row slab
  const int lcol = (((lane & 7) ^ lrow) * 8);

  const _Float16* pA[4];
  const _Float16* pB[4];
  _Float16* dA[4];
  _Float16* dB[4];
  #pragma unroll
  for (int j = 0; j < 4; ++j) {
    int r = w * 32 + j * 8;
    pA[j] = A + (long long)(bm * 128 + r + lrow) * K + lcol;
    pB[j] = B + (long long)(bn * 128 + r + lrow) * K + lcol;
    dA[j] = &lA[r * 64];
    dB[j] = &lB[r * 64];
  }

  const int coff = (((lr >> 2) & 1) * 32) | ((lg ^ (lr & 3)) * 8);

  floatx4 acc[4][4];
  #pragma unroll
  for (int i = 0; i < 4; ++i)
    #pragma unroll
    for (int j = 0; j < 4; ++j) { acc[i][j][0]=0.f; acc[i][j][1]=0.f; acc[i][j][2]=0.f; acc[i][j][3]=0.f; }

  const int nk = K >> 6;
  for (int kt = 0; kt < nk; ++kt) {
    __syncthreads();
    #pragma unroll
    for (int j = 0; j < 4; ++j) {
      async16(pA[j], dA[j]);
      async16(pB[j], dB[j]);
      pA[j] += 64; pB[j] += 64;
    }
    __syncthreads();
    #pragma unroll
    for (int s = 0; s < 2; ++s) {
      const int so = coff ^ (s * 32);
      half8 af[4], bf[4];
      #pragma unroll
      for (int mi = 0; mi < 4; ++mi)
        af[mi] = *(const half8*)&lA[(wm * 64 + mi * 16 + lr) * 64 + so];
      #pragma unroll
      for (int ni = 0; ni < 4; ++ni)
        bf[ni] = *(const half8*)&lB[(wn * 64 + ni * 16 + lr) * 64 + so];
      #pragma unroll
      for (int mi = 0; mi < 4; ++mi)
        #pragma unroll
        for (int ni = 0; ni < 4; ++ni)
          acc[mi][ni] = __builtin_amdgcn_mfma_f32_16x16x32_f16(
              af[mi], bf[ni], acc[mi][ni], 0, 0, 0);
    }
  }

  float bvs[4];
  #pragma unroll
  for (int ni = 0; ni < 4; ++ni) {
    int gc = bn * 128 + wn * 64 + ni * 16 + lr;
    bvs[ni] = bias ? bias[gc & (C_DIM - 1)] : 0.0f;
  }
  #pragma unroll
  for (int mi = 0; mi < 4; ++mi)
    #pragma unroll
    for (int ni = 0; ni < 4; ++ni) {
      int gc = bn * 128 + wn * 64 + ni * 16 + lr;
      #pragma unroll
      for (int i = 0; i < 4; ++i) {
        int gr = bm * 128 + wm * 64 + mi * 16 + lg * 4 + i;
        float v = acc[mi][ni][i] + bvs[ni];
        long long idx = (long long)gr * N + gc;
        if constexpr (EPI == 1) ((float*)outv)[idx] = v;
        else                    ((_Float16*)outv)[idx] = (_Float16)v;
      }
    }
}

// ---------------------------------------------------------------- aggregation (+reference's reshape)
__global__ __launch_bounds__(256) void aggregate_kernel(
    const _Float16* __restrict__ V, const float* __restrict__ wgt,
    const int* __restrict__ dly, _Float16* __restrict__ V2) {
  int b = blockIdx.x & 7;                         // batch pinned to XCD
  int g = (blockIdx.x >> 3) * 256 + threadIdx.x;  // 0 .. T*C/8-1
  int c8 = g & 127;
  int tp = g >> 7;
  int h = tp >> 7, lhi = tp & 127;
  int cp = c8 << 3;
  int e0 = cp & 63, lo = cp >> 6;
  int l = lhi * 16 + lo;
  int ch = h * 64 + e0;
  float acc[8];
  #pragma unroll
  for (int j = 0; j < 8; ++j) acc[j] = 0.0f;
  const long long vbase = (long long)b * T_LEN * C_DIM;
  for (int k = 0; k < TOPK; ++k) {
    float w = wgt[b * TOPK + k];
    int d = dly[b * TOPK + k];
    int ts = (l + d) & (T_LEN - 1);
    half8 vv = *(const half8*)(V + vbase + (long long)ts * C_DIM + ch);
    #pragma unroll
    for (int j = 0; j < 8; ++j) acc[j] += w * (float)vv[j];
  }
  half8 o;
  #pragma unroll
  for (int j = 0; j < 8; ++j) o[j] = (_Float16)acc[j];
  __builtin_nontemporal_store(o, (half8*)(V2 + vbase + (long long)tp * C_DIM + cp));
}

// ---------------------------------------------------------------- launcher
extern "C" void kernel_launch(void* const* d_in, const int* in_sizes, int n_in,
                              void* d_out, int out_size, void* d_ws, size_t ws_size,
                              hipStream_t stream) {
  const float* x  = (const float*)d_in[0];
  const float* Wq = (const float*)d_in[1];
  const float* Wk = (const float*)d_in[3];
  const float* Wv = (const float*)d_in[5];
  const float* bv = (const float*)d_in[6];
  const float* Wp = (const float*)d_in[7];
  const float* bp = (const float*)d_in[8];
  // bq/bk provably irrelevant (constant shift of corr; top-k order & softmax shift-invariant)

  // corr path: Q.K^T == X (Wq Wk^T) X^T; corr[l] = sum_c circcorr(XM_c, x_c)[l]
  //            computed in O(N log N) per channel via FFT cross-spectrum.
  // d_out (64 MiB):
  //   [0,32M)  xh fp16 (live until Xt transpose) -> then spec(66K)+twg(8K)
  //   [32,64M) Wqh/Wkh/Wvt/Mt2 (2M each, dead after XM & V GEMMs) -> then XMt (32M)
  // ws (>= 64MiB + 72KiB proven):
  //   [0,32M)  XMh -> Xt -> V2      [32,64M) V -> Wpt      tail: wgt, dly
  const size_t SZ_H = (size_t)B_DIM * T_LEN * C_DIM * 2;   // 32 MiB
  const size_t NEEDED = 2 * SZ_H + 65536 + 8192;
  if (ws_size < NEEDED) return;

  char* ws = (char*)d_ws;
  _Float16* XMh = (_Float16*)ws;
  _Float16* V   = (_Float16*)(ws + SZ_H);
  float* wgt   = (float*)(ws + 2 * SZ_H + 65536);
  int*   dly   = (int*)(ws + 2 * SZ_H + 65536 + 4096);
  _Float16* Xt  = (_Float16*)ws;             // after XM transpose (XMh dead)
  _Float16* V2  = (_Float16*)ws;             // after fft_corr (Xt dead)
  _Float16* Wpt = (_Float16*)(ws + SZ_H);    // after agg (V dead), 2 MiB

  char* dob = (char*)d_out;
  _Float16* xh  = (_Float16*)dob;
  float*    spec = (float*)dob;                        // after xh dead: 66 KiB
  float*    twg  = (float*)(dob + 131072);             // 8 KiB
  _Float16* Wqh = (_Float16*)(dob + 32 * 1048576);
  _Float16* Wkh = (_Float16*)(dob + 34 * 1048576);
  _Float16* Wvt = (_Float16*)(dob + 36 * 1048576);
  _Float16* Mt2 = (_Float16*)(dob + 38 * 1048576);
  _Float16* XMt = (_Float16*)(dob + 32 * 1048576);     // after weights dead: 32 MiB

  const int M = B_DIM * T_LEN;  // 16384

  cvt_f16_kernel<<<(M * C_DIM / 8) / 256, 256, 0, stream>>>(x, xh, M * C_DIM / 8);
  cvt_f16_kernel<<<(C_DIM * C_DIM / 8) / 256, 256, 0, stream>>>(Wq, Wqh, C_DIM * C_DIM / 8);
  cvt_f16_kernel<<<(C_DIM * C_DIM / 8) / 256, 256, 0, stream>>>(Wk, Wkh, C_DIM * C_DIM / 8);

  dim3 tgrid(16, 16, 1);
  wt3_kernel<<<tgrid, 256, 0, stream>>>(Wv, Wv, Wv, Wvt, Wvt, Wvt);   // z=0 slice only

  dim3 pgrid(M / 128, C_DIM / 128, 1);        // (128, 8)
  dim3 mgrid(C_DIM / 128, C_DIM / 128, 1);    // (8, 8)

  // Mt2[m,n] = sum_o Wk[m,o] * Wq[n,o]
  gemm_f16_kernel<0><<<mgrid, 256, 0, stream>>>(Wkh, Wqh, nullptr, Mt2, C_DIM, C_DIM);
  // XM[t,c] = sum_a x[t,a] * Mt2[c,a] = sum_o Q[t,o] Wk[c,o]
  gemm_f16_kernel<0><<<pgrid, 256, 0, stream>>>(xh, Mt2, nullptr, XMh, C_DIM, C_DIM);
  // V = xh @ Wvt + bv   (before transposes so Wvt dies before XMt overlays it)
  gemm_f16_kernel<0><<<pgrid, 256, 0, stream>>>(xh, Wvt, bv, V, C_DIM, C_DIM);

  dim3 trgrid(T_LEN / 64, C_DIM / 64, B_DIM); // (32, 16, 8)
  tr16_kernel<<<trgrid, 256, 0, stream>>>(XMh, XMt);   // XMh dead after
  tr16_kernel<<<trgrid, 256, 0, stream>>>(xh, Xt);     // xh dead after

  zero_kernel<<<(B_DIM * SPEC_ST + 255) / 256, 256, 0, stream>>>(spec, B_DIM * SPEC_ST);
  twiddle_kernel<<<4, 256, 0, stream>>>(twg);

  fft_corr_kernel<<<B_DIM * (C_DIM / CG), 256, 0, stream>>>(XMt, Xt, twg, spec);
  ifft_topk_kernel<<<B_DIM, 256, 0, stream>>>(spec, twg, wgt, dly);

  aggregate_kernel<<<(T_LEN * C_DIM / 8 / 256) * B_DIM, 256, 0, stream>>>(V, wgt, dly, V2);

  wt3_kernel<<<tgrid, 256, 0, stream>>>(Wp, Wp, Wp, Wpt, Wpt, Wpt);  // z=0 slice only

  // out = V2 @ Wpt + bp -> d_out f32 (spec/twg/XMt dead)
  gemm_f16_kernel<1><<<pgrid, 256, 0, stream>>>(V2, Wpt, bp, d_out, C_DIM, C_DIM);
}

// Round 6
// 505.283 us; speedup vs baseline: 1.3221x; 1.0471x over previous
//
#include <hip/hip_runtime.h>

// Problem constants (B,T,C,H,E = 8,2048,1024,16,64; TOP_K=38)
#define T_LEN 2048
#define B_DIM 8
#define C_DIM 1024
#define TOPK  38
#define FFT_N 2048
#define SPEC_ST 2050   // floats per batch: 1025 complex (k=0..1024)

typedef _Float16 half8 __attribute__((ext_vector_type(8)));
typedef float  floatx4 __attribute__((ext_vector_type(4)));
typedef unsigned int u32;

__device__ __forceinline__ void async16(const void* g, void* l) {
  __builtin_amdgcn_global_load_lds(
      (const __attribute__((address_space(1))) u32*)g,
      (__attribute__((address_space(3))) u32*)l, 16, 0, 0);
}

__device__ __forceinline__ int rev11(int x) { return (int)(__brev((u32)x) >> 21); }
// LDS bank swizzle (bijective): XOR high addr bits into bank field.
__device__ __forceinline__ int SW(int a) { return a ^ ((a >> 5) & 31); }

struct cpx { float r, i; };
__device__ __forceinline__ cpx csqr(cpx a) { return {a.r*a.r - a.i*a.i, 2.0f*a.r*a.i}; }
// multiply by W^(256*m) = e^{-i pi m/4}
__device__ __forceinline__ cpx c8m(cpx a, int m) {
  const float R2 = 0.70710678118654752f;
  switch (m & 3) {
    case 0:  return a;
    case 1:  return {R2*(a.r + a.i), R2*(a.i - a.r)};
    case 2:  return {a.i, -a.r};
    default: return {R2*(a.i - a.r), -R2*(a.r + a.i)};
  }
}

// Three DIF stages (distances 4,2,1 in units of the ownership stride) on 8
// register-resident points. tb = W^(lane_sub * tstep_of_first_stage).
// Stage a: pairs (m,m+4), tw = tb * W^(256m); stage b: pairs (m,m+2),
// tw = tb^2 * W^(512(m&1)); stage c: pairs (m,m+1), tw = tb^4.
__device__ __forceinline__ void radix8(float zr[8], float zi[8], cpx tb) {
  cpx tb2 = csqr(tb), tb4 = csqr(tb2);
  #pragma unroll
  for (int m = 0; m < 4; ++m) {
    cpx tw = c8m(tb, m);
    float ur = zr[m], ui = zi[m], vr = zr[m+4], vi = zi[m+4];
    zr[m] = ur + vr; zi[m] = ui + vi;
    float sr = ur - vr, si = ui - vi;
    zr[m+4] = sr*tw.r - si*tw.i; zi[m+4] = sr*tw.i + si*tw.r;
  }
  cpx twb = c8m(tb2, 2);
  #pragma unroll
  for (int h = 0; h < 2; ++h) {
    int b0 = h * 4;
    { cpx tw = tb2;
      float ur = zr[b0], ui = zi[b0], vr = zr[b0+2], vi = zi[b0+2];
      zr[b0] = ur + vr; zi[b0] = ui + vi;
      float sr = ur - vr, si = ui - vi;
      zr[b0+2] = sr*tw.r - si*tw.i; zi[b0+2] = sr*tw.i + si*tw.r; }
    { cpx tw = twb;
      float ur = zr[b0+1], ui = zi[b0+1], vr = zr[b0+3], vi = zi[b0+3];
      zr[b0+1] = ur + vr; zi[b0+1] = ui + vi;
      float sr = ur - vr, si = ui - vi;
      zr[b0+3] = sr*tw.r - si*tw.i; zi[b0+3] = sr*tw.i + si*tw.r; }
  }
  #pragma unroll
  for (int p = 0; p < 8; p += 2) {
    float ur = zr[p], ui = zi[p], vr = zr[p+1], vi = zi[p+1];
    zr[p] = ur + vr; zi[p] = ui + vi;
    float sr = ur - vr, si = ui - vi;
    zr[p+1] = sr*tb4.r - si*tb4.i; zi[p+1] = sr*tb4.i + si*tb4.r;
  }
}

// ---------------------------------------------------------------- zero fill
__global__ __launch_bounds__(256) void zero_kernel(float* __restrict__ p, int n) {
  int i = blockIdx.x * 256 + threadIdx.x;
  if (i < n) p[i] = 0.0f;
}

// ---------------------------------------------------------------- f32 -> fp16 (8/thread)
__global__ __launch_bounds__(256) void cvt_f16_kernel(
    const float* __restrict__ src, _Float16* __restrict__ dst, int n8) {
  int i = blockIdx.x * 256 + threadIdx.x;
  if (i >= n8) return;
  floatx4 a = ((const floatx4*)src)[i * 2];
  floatx4 b = ((const floatx4*)src)[i * 2 + 1];
  half8 o;
  #pragma unroll
  for (int j = 0; j < 4; ++j) { o[j] = (_Float16)a[j]; o[j + 4] = (_Float16)b[j]; }
  ((half8*)dst)[i] = o;
}

// ---------------------------------------------------------------- W [K,N] f32 -> Wt [N,K] fp16 (batched x3)
__global__ __launch_bounds__(256) void wt3_kernel(
    const float* __restrict__ w0, const float* __restrict__ w1,
    const float* __restrict__ w2, _Float16* __restrict__ d0,
    _Float16* __restrict__ d1, _Float16* __restrict__ d2) {
  const float* src = blockIdx.z == 0 ? w0 : (blockIdx.z == 1 ? w1 : w2);
  _Float16*    dst = blockIdx.z == 0 ? d0 : (blockIdx.z == 1 ? d1 : d2);
  __shared__ _Float16 tile[64][65];
  int k0 = blockIdx.y * 64, n0 = blockIdx.x * 64;
  int tx = threadIdx.x & 63, ty = threadIdx.x >> 6;  // ty 0..3
  #pragma unroll
  for (int j = 0; j < 16; ++j) {
    int r = j * 4 + ty;
    tile[r][tx] = (_Float16)src[(size_t)(k0 + r) * C_DIM + n0 + tx];
  }
  __syncthreads();
  #pragma unroll
  for (int j = 0; j < 16; ++j) {
    int r = j * 4 + ty;
    dst[(size_t)(n0 + r) * C_DIM + k0 + tx] = tile[tx][r];
  }
}

// ---------------------------------------------------------------- fp16 [B][T][C] -> [B][C][T] transpose
__global__ __launch_bounds__(256) void tr16_kernel(
    const _Float16* __restrict__ src, _Float16* __restrict__ dst) {
  __shared__ _Float16 tile[64][65];
  int b = blockIdx.z;
  int t0 = blockIdx.x * 64, c0 = blockIdx.y * 64;
  const _Float16* s = src + (size_t)b * T_LEN * C_DIM;
  _Float16* d = dst + (size_t)b * C_DIM * T_LEN;
  int tid = threadIdx.x;
  int c8 = (tid & 7) * 8, tr = tid >> 3;          // tr 0..31
  #pragma unroll
  for (int h = 0; h < 2; ++h) {
    int r = tr + h * 32;
    half8 v = *(const half8*)&s[(size_t)(t0 + r) * C_DIM + c0 + c8];
    #pragma unroll
    for (int j = 0; j < 8; ++j) tile[r][c8 + j] = v[j];
  }
  __syncthreads();
  int t8 = (tid & 7) * 8, cr = tid >> 3;
  #pragma unroll
  for (int h = 0; h < 2; ++h) {
    int c = cr + h * 32;
    half8 o;
    #pragma unroll
    for (int j = 0; j < 8; ++j) o[j] = tile[t8 + j][c];
    *(half8*)&d[(size_t)(c0 + c) * T_LEN + t0 + t8] = o;
  }
}

// ---------------------------------------------------------------- twiddles tw[k] = exp(-i*pi*k/1024), k<1024
__global__ __launch_bounds__(256) void twiddle_kernel(float* __restrict__ twg) {
  int k = blockIdx.x * 256 + threadIdx.x;
  if (k < FFT_N / 2) {
    float th = -3.14159265358979323846f * (float)k / 1024.0f;
    twg[2 * k]     = cosf(th);
    twg[2 * k + 1] = sinf(th);
  }
}

// ---------------------------------------------------------------- per-channel FFT cross-spectrum
// Register-resident radix-8 DIF: 2048 = 8*8*8*4. Thread owns 8 points.
//   Phase A: i = tid + 256m      (stages 0-2, tb = W^tid)
//   Phase B: i = 256blk+32m+lo5  (stages 3-5, tb = W^(8 lo5))
//   Phase C: i = 32g+4m+lo2      (stages 6-8, tb = W^(64 lo2))
//   Stages 9,10: partners are lanes tid^2 / tid^1 -> __shfl_xor, no LDS.
// Exchanges via SW-swizzled LDS (<=4-way). Output bit-reversed; separation +
// register cross-spectrum accumulation identical to the verified r5 kernel.
#define CG 8
__global__ __launch_bounds__(256) void fft_corr_kernel(
    const _Float16* __restrict__ XMt, const _Float16* __restrict__ Xt,
    const float* __restrict__ twg, float* __restrict__ spec) {
  __shared__ float re[FFT_N], im[FFT_N];
  __shared__ float twr[FFT_N / 2], twi[FFT_N / 2];
  const int tid = threadIdx.x;
  const int b = blockIdx.x >> 7;                 // 128 blocks per batch
  const int cg0 = (blockIdx.x & 127) * CG;
  for (int i = tid; i < FFT_N / 2; i += 256) { twr[i] = twg[2 * i]; twi[i] = twg[2 * i + 1]; }
  const int lo5 = tid & 31, blk = tid >> 5;
  const int lo2 = tid & 3,  g   = tid >> 2;
  const _Float16* xmB = XMt + (size_t)b * C_DIM * T_LEN;
  const _Float16* xB  = Xt  + (size_t)b * C_DIM * T_LEN;
  float sRa[4] = {0.f, 0.f, 0.f, 0.f};
  float sIa[4] = {0.f, 0.f, 0.f, 0.f};
  float s1024 = 0.f;
  float zr[8], zi[8], nr[8], ni[8];
  // prefetch channel 0 (stride-256 ownership: per-instr 64 consecutive fp16)
  #pragma unroll
  for (int m = 0; m < 8; ++m) {
    nr[m] = (float)xmB[(size_t)cg0 * T_LEN + tid + 256 * m];
    ni[m] = (float)xB [(size_t)cg0 * T_LEN + tid + 256 * m];
  }
  __syncthreads();
  cpx tA = {twr[tid],      twi[tid]};       // W^tid
  cpx tB = {twr[8 * lo5],  twi[8 * lo5]};   // W^(8 lo5)
  cpx tC = {twr[64 * lo2], twi[64 * lo2]};  // W^(64 lo2)
  for (int cc = 0; cc < CG; ++cc) {
    #pragma unroll
    for (int m = 0; m < 8; ++m) { zr[m] = nr[m]; zi[m] = ni[m]; }
    if (cc + 1 < CG) {
      const size_t off = (size_t)(cg0 + cc + 1) * T_LEN;
      #pragma unroll
      for (int m = 0; m < 8; ++m) {
        nr[m] = (float)xmB[off + tid + 256 * m];
        ni[m] = (float)xB [off + tid + 256 * m];
      }
    }
    radix8(zr, zi, tA);                          // stages 0-2
    __syncthreads();                             // prev separation reads done
    #pragma unroll
    for (int m = 0; m < 8; ++m) { int a = SW(tid + 256 * m); re[a] = zr[m]; im[a] = zi[m]; }
    __syncthreads();
    #pragma unroll
    for (int m = 0; m < 8; ++m) { int a = SW(256 * blk + 32 * m + lo5); zr[m] = re[a]; zi[m] = im[a]; }
    radix8(zr, zi, tB);                          // stages 3-5
    __syncthreads();                             // all ex1 reads done
    #pragma unroll
    for (int m = 0; m < 8; ++m) { int a = SW(256 * blk + 32 * m + lo5); re[a] = zr[m]; im[a] = zi[m]; }
    __syncthreads();
    #pragma unroll
    for (int m = 0; m < 8; ++m) { int a = SW(32 * g + 4 * m + lo2); zr[m] = re[a]; zi[m] = im[a]; }
    radix8(zr, zi, tC);                          // stages 6-8
    // stage 9: distance 2 -> lanes tid^2; upper twiddle W^(512*(tid&1))
    #pragma unroll
    for (int m = 0; m < 8; ++m) {
      float pr = __shfl_xor(zr[m], 2), pi = __shfl_xor(zi[m], 2);
      if ((tid & 2) == 0) { zr[m] += pr; zi[m] += pi; }
      else {
        float sr = pr - zr[m], si = pi - zi[m];
        if (tid & 1) { zr[m] = si; zi[m] = -sr; }   // *( -i )
        else         { zr[m] = sr; zi[m] = si; }
      }
    }
    // stage 10: distance 1 -> lanes tid^1; twiddle 1
    #pragma unroll
    for (int m = 0; m < 8; ++m) {
      float pr = __shfl_xor(zr[m], 1), pi = __shfl_xor(zi[m], 1);
      if ((tid & 1) == 0) { zr[m] += pr; zi[m] += pi; }
      else                { zr[m] = pr - zr[m]; zi[m] = pi - zi[m]; }
    }
    __syncthreads();                             // all ex2 reads done
    #pragma unroll
    for (int m = 0; m < 8; ++m) { int a = SW(32 * g + 4 * m + lo2); re[a] = zr[m]; im[a] = zi[m]; }
    __syncthreads();
    // separation + register accumulation (k = tid + 256r) -- verified r5 code
    #pragma unroll
    for (int r = 0; r < 4; ++r) {
      int k = tid + r * 256;
      if (k == 0) {
        sRa[0] += re[0] * im[0];                  // S[0]    (Z[0] at pos 0)
        s1024  += re[1] * im[1];                  // S[1024] (Z[1024] at pos rev=1)
      } else {
        int pk = SW(rev11(k)), pn = SW(rev11(FFT_N - k));
        float zr_ = re[pk], zi_ = im[pk], yr = re[pn], yi = im[pn];
        float ar = 0.5f * (zr_ + yr), ai = 0.5f * (zi_ - yi);   // XMf[k]
        float br = 0.5f * (zi_ + yi), bi = -0.5f * (zr_ - yr);  // Xf[k]
        sRa[r] += ar * br + ai * bi;              // Re(XMf*conj(Xf))
        sIa[r] += ai * br - ar * bi;              // Im
      }
    }
  }
  float* sb = spec + (size_t)b * SPEC_ST;
  #pragma unroll
  for (int r = 0; r < 4; ++r) {
    int k = tid + r * 256;
    atomicAdd(&sb[2 * k],     sRa[r]);
    atomicAdd(&sb[2 * k + 1], sIa[r]);
  }
  if (tid == 0) atomicAdd(&sb[2048], s1024);
}

// ---------------------------------------------------------------- inverse FFT + top-k + softmax
// Load k=0..1024, Hermitian-mirror to 1025..2047; conj-twiddle DIF (= N*IDFT,
// bit-rev output); vals[rev(p)] = re[p]/(2048*1024) == reference mean_value.
__global__ __launch_bounds__(256) void ifft_topk_kernel(
    const float* __restrict__ spec, const float* __restrict__ twg,
    float* __restrict__ wgt, int* __restrict__ dly) {
  __shared__ float re[FFT_N], im[FFT_N];
  __shared__ float twr[FFT_N / 2], twi[FFT_N / 2];
  __shared__ float vals[FFT_N];
  __shared__ float swv[4];
  __shared__ int   swidx[4];
  __shared__ float selw[TOPK];
  __shared__ int   seli[TOPK];
  int b = blockIdx.x, tid = threadIdx.x;
  for (int i = tid; i < FFT_N / 2; i += 256) { twr[SW(i)] = twg[2 * i]; twi[SW(i)] = twg[2 * i + 1]; }
  const float* sb = spec + (size_t)b * SPEC_ST;
  for (int i = tid; i < FFT_N; i += 256) {
    int src = (i <= 1024) ? i : (FFT_N - i);
    float sgn = (i <= 1024) ? 1.0f : -1.0f;
    re[SW(i)] = sb[2 * src];
    im[SW(i)] = sgn * sb[2 * src + 1];
  }
  __syncthreads();
  #pragma unroll 1
  for (int s = 0; s < 11; ++s) {
    const int half = 1024 >> s, tstep = 1 << s;
    #pragma unroll
    for (int r = 0; r < 4; ++r) {
      int idx = tid + r * 256;
      int j = idx & (half - 1);
      int i0 = SW(2 * idx - j), i1 = SW(2 * idx - j + half);
      float ur = re[i0], ui = im[i0], vr = re[i1], vi = im[i1];
      float sr = ur - vr, si = ui - vi;
      int tix = SW(j * tstep);
      float wr = twr[tix], wi = twi[tix];
      re[i0] = ur + vr; im[i0] = ui + vi;
      re[i1] = sr * wr + si * wi;          // (sr+i si)*conj(w)
      im[i1] = si * wr - sr * wi;
    }
    __syncthreads();
  }
  const float sc = 1.0f / 2097152.0f;      // 1/2048 (IDFT) * 1/1024 (channel mean)
  for (int i = tid; i < FFT_N; i += 256) vals[SW(rev11(i))] = re[SW(i)] * sc;
  __syncthreads();
  for (int it = 0; it < TOPK; ++it) {
    float bv = -3.4e38f; int bi = T_LEN - 1;
    for (int i = tid; i < T_LEN; i += 256) {
      float v = vals[SW(i)];
      if (v > bv || (v == bv && i < bi)) { bv = v; bi = i; }
    }
    #pragma unroll
    for (int off = 32; off > 0; off >>= 1) {
      float ov = __shfl_down(bv, off);
      int   oi = __shfl_down(bi, off);
      if (ov > bv || (ov == bv && oi < bi)) { bv = ov; bi = oi; }
    }
    if ((tid & 63) == 0) { swv[tid >> 6] = bv; swidx[tid >> 6] = bi; }
    __syncthreads();
    if (tid == 0) {
      #pragma unroll
      for (int ww = 1; ww < 4; ++ww) {
        float ov = swv[ww]; int oi = swidx[ww];
        if (ov > bv || (ov == bv && oi < bi)) { bv = ov; bi = oi; }
      }
      if (bi < 0) bi = 0; if (bi > T_LEN - 1) bi = T_LEN - 1;
      selw[it] = bv; seli[it] = bi;
      vals[SW(bi)] = -3.4e38f;
    }
    __syncthreads();
  }
  if (tid == 0) {
    float m = selw[0], s = 0.0f, e[TOPK];
    for (int i = 0; i < TOPK; ++i) { e[i] = expf(selw[i] - m); s += e[i]; }
    float inv = 1.0f / s;
    for (int i = 0; i < TOPK; ++i) { wgt[b * TOPK + i] = e[i] * inv; dly[b * TOPK + i] = seli[i]; }
  }
}

// ---------------------------------------------------------------- fp16 NT GEMM (m97-style + read swizzle)
// C[m,n] = sum_k A[m*K+k]*B[n*K+k]; EPI: 0 = fp16 store + bias, 1 = f32 store + bias.
// Source-chunk swizzle chunk' = chunk ^ (row&7) keeps LDS dest linear (rule 21)
// and makes fragment reads 2-way max (conflicts measured 0 in round 3).
template <int EPI>
__global__ __launch_bounds__(256, 3) void gemm_f16_kernel(
    const _Float16* __restrict__ A, const _Float16* __restrict__ B,
    const float* __restrict__ bias, void* __restrict__ outv, int N, int K) {
  __shared__ __align__(16) _Float16 lA[128 * 64];
  __shared__ __align__(16) _Float16 lB[128 * 64];

  const int tid = threadIdx.x;
  const int bm = blockIdx.x, bn = blockIdx.y;
  const int lane = tid & 63, w = tid >> 6;
  const int wm = w >> 1, wn = w & 1;     // 2x2 waves -> 64x64 tiles
  const int lr = lane & 15, lg = lane >> 4;

  const int lrow = lane >> 3;            // 0..7 = row within 8-row slab
  const int lcol = (((lane & 7) ^ lrow) * 8);

  const _Float16* pA[4];
  const _Float16* pB[4];
  _Float16* dA[4];
  _Float16* dB[4];
  #pragma unroll
  for (int j = 0; j < 4; ++j) {
    int r = w * 32 + j * 8;
    pA[j] = A + (long long)(bm * 128 + r + lrow) * K + lcol;
    pB[j] = B + (long long)(bn * 128 + r + lrow) * K + lcol;
    dA[j] = &lA[r * 64];
    dB[j] = &lB[r * 64];
  }

  const int coff = (((lr >> 2) & 1) * 32) | ((lg ^ (lr & 3)) * 8);

  floatx4 acc[4][4];
  #pragma unroll
  for (int i = 0; i < 4; ++i)
    #pragma unroll
    for (int j = 0; j < 4; ++j) { acc[i][j][0]=0.f; acc[i][j][1]=0.f; acc[i][j][2]=0.f; acc[i][j][3]=0.f; }

  const int nk = K >> 6;
  for (int kt = 0; kt < nk; ++kt) {
    __syncthreads();
    #pragma unroll
    for (int j = 0; j < 4; ++j) {
      async16(pA[j], dA[j]);
      async16(pB[j], dB[j]);
      pA[j] += 64; pB[j] += 64;
    }
    __syncthreads();
    #pragma unroll
    for (int s = 0; s < 2; ++s) {
      const int so = coff ^ (s * 32);
      half8 af[4], bf[4];
      #pragma unroll
      for (int mi = 0; mi < 4; ++mi)
        af[mi] = *(const half8*)&lA[(wm * 64 + mi * 16 + lr) * 64 + so];
      #pragma unroll
      for (int ni = 0; ni < 4; ++ni)
        bf[ni] = *(const half8*)&lB[(wn * 64 + ni * 16 + lr) * 64 + so];
      #pragma unroll
      for (int mi = 0; mi < 4; ++mi)
        #pragma unroll
        for (int ni = 0; ni < 4; ++ni)
          acc[mi][ni] = __builtin_amdgcn_mfma_f32_16x16x32_f16(
              af[mi], bf[ni], acc[mi][ni], 0, 0, 0);
    }
  }

  float bvs[4];
  #pragma unroll
  for (int ni = 0; ni < 4; ++ni) {
    int gc = bn * 128 + wn * 64 + ni * 16 + lr;
    bvs[ni] = bias ? bias[gc & (C_DIM - 1)] : 0.0f;
  }
  #pragma unroll
  for (int mi = 0; mi < 4; ++mi)
    #pragma unroll
    for (int ni = 0; ni < 4; ++ni) {
      int gc = bn * 128 + wn * 64 + ni * 16 + lr;
      #pragma unroll
      for (int i = 0; i < 4; ++i) {
        int gr = bm * 128 + wm * 64 + mi * 16 + lg * 4 + i;
        float v = acc[mi][ni][i] + bvs[ni];
        long long idx = (long long)gr * N + gc;
        if constexpr (EPI == 1) ((float*)outv)[idx] = v;
        else                    ((_Float16*)outv)[idx] = (_Float16)v;
      }
    }
}

// ---------------------------------------------------------------- aggregation (+reference's reshape)
__global__ __launch_bounds__(256) void aggregate_kernel(
    const _Float16* __restrict__ V, const float* __restrict__ wgt,
    const int* __restrict__ dly, _Float16* __restrict__ V2) {
  int b = blockIdx.x & 7;                         // batch pinned to XCD
  int g = (blockIdx.x >> 3) * 256 + threadIdx.x;  // 0 .. T*C/8-1
  int c8 = g & 127;
  int tp = g >> 7;
  int h = tp >> 7, lhi = tp & 127;
  int cp = c8 << 3;
  int e0 = cp & 63, lo = cp >> 6;
  int l = lhi * 16 + lo;
  int ch = h * 64 + e0;
  float acc[8];
  #pragma unroll
  for (int j = 0; j < 8; ++j) acc[j] = 0.0f;
  const long long vbase = (long long)b * T_LEN * C_DIM;
  for (int k = 0; k < TOPK; ++k) {
    float w = wgt[b * TOPK + k];
    int d = dly[b * TOPK + k];
    int ts = (l + d) & (T_LEN - 1);
    half8 vv = *(const half8*)(V + vbase + (long long)ts * C_DIM + ch);
    #pragma unroll
    for (int j = 0; j < 8; ++j) acc[j] += w * (float)vv[j];
  }
  half8 o;
  #pragma unroll
  for (int j = 0; j < 8; ++j) o[j] = (_Float16)acc[j];
  __builtin_nontemporal_store(o, (half8*)(V2 + vbase + (long long)tp * C_DIM + cp));
}

// ---------------------------------------------------------------- launcher
extern "C" void kernel_launch(void* const* d_in, const int* in_sizes, int n_in,
                              void* d_out, int out_size, void* d_ws, size_t ws_size,
                              hipStream_t stream) {
  const float* x  = (const float*)d_in[0];
  const float* Wq = (const float*)d_in[1];
  const float* Wk = (const float*)d_in[3];
  const float* Wv = (const float*)d_in[5];
  const float* bv = (const float*)d_in[6];
  const float* Wp = (const float*)d_in[7];
  const float* bp = (const float*)d_in[8];
  // bq/bk provably irrelevant (constant shift of corr; top-k order & softmax shift-invariant)

  // corr path: Q.K^T == X (Wq Wk^T) X^T; corr[l] = sum_c circcorr(XM_c, x_c)[l]
  //            computed in O(N log N) per channel via FFT cross-spectrum.
  // d_out (64 MiB):
  //   [0,32M)  xh fp16 (live until Xt transpose) -> then spec(66K)+twg(8K)
  //   [32,64M) Wqh/Wkh/Wvt/Mt2 (2M each, dead after XM & V GEMMs) -> then XMt (32M)
  // ws (>= 64MiB + 72KiB proven):
  //   [0,32M)  XMh -> Xt -> V2      [32,64M) V -> Wpt      tail: wgt, dly
  const size_t SZ_H = (size_t)B_DIM * T_LEN * C_DIM * 2;   // 32 MiB
  const size_t NEEDED = 2 * SZ_H + 65536 + 8192;
  if (ws_size < NEEDED) return;

  char* ws = (char*)d_ws;
  _Float16* XMh = (_Float16*)ws;
  _Float16* V   = (_Float16*)(ws + SZ_H);
  float* wgt   = (float*)(ws + 2 * SZ_H + 65536);
  int*   dly   = (int*)(ws + 2 * SZ_H + 65536 + 4096);
  _Float16* Xt  = (_Float16*)ws;             // after XM transpose (XMh dead)
  _Float16* V2  = (_Float16*)ws;             // after fft_corr (Xt dead)
  _Float16* Wpt = (_Float16*)(ws + SZ_H);    // after agg (V dead), 2 MiB

  char* dob = (char*)d_out;
  _Float16* xh  = (_Float16*)dob;
  float*    spec = (float*)dob;                        // after xh dead: 66 KiB
  float*    twg  = (float*)(dob + 131072);             // 8 KiB
  _Float16* Wqh = (_Float16*)(dob + 32 * 1048576);
  _Float16* Wkh = (_Float16*)(dob + 34 * 1048576);
  _Float16* Wvt = (_Float16*)(dob + 36 * 1048576);
  _Float16* Mt2 = (_Float16*)(dob + 38 * 1048576);
  _Float16* XMt = (_Float16*)(dob + 32 * 1048576);     // after weights dead: 32 MiB

  const int M = B_DIM * T_LEN;  // 16384

  cvt_f16_kernel<<<(M * C_DIM / 8) / 256, 256, 0, stream>>>(x, xh, M * C_DIM / 8);
  cvt_f16_kernel<<<(C_DIM * C_DIM / 8) / 256, 256, 0, stream>>>(Wq, Wqh, C_DIM * C_DIM / 8);
  cvt_f16_kernel<<<(C_DIM * C_DIM / 8) / 256, 256, 0, stream>>>(Wk, Wkh, C_DIM * C_DIM / 8);

  dim3 tgrid(16, 16, 1);
  wt3_kernel<<<tgrid, 256, 0, stream>>>(Wv, Wv, Wv, Wvt, Wvt, Wvt);   // z=0 slice only

  dim3 pgrid(M / 128, C_DIM / 128, 1);        // (128, 8)
  dim3 mgrid(C_DIM / 128, C_DIM / 128, 1);    // (8, 8)

  // Mt2[m,n] = sum_o Wk[m,o] * Wq[n,o]
  gemm_f16_kernel<0><<<mgrid, 256, 0, stream>>>(Wkh, Wqh, nullptr, Mt2, C_DIM, C_DIM);
  // XM[t,c] = sum_a x[t,a] * Mt2[c,a] = sum_o Q[t,o] Wk[c,o]
  gemm_f16_kernel<0><<<pgrid, 256, 0, stream>>>(xh, Mt2, nullptr, XMh, C_DIM, C_DIM);
  // V = xh @ Wvt + bv   (before transposes so Wvt dies before XMt overlays it)
  gemm_f16_kernel<0><<<pgrid, 256, 0, stream>>>(xh, Wvt, bv, V, C_DIM, C_DIM);

  dim3 trgrid(T_LEN / 64, C_DIM / 64, B_DIM); // (32, 16, 8)
  tr16_kernel<<<trgrid, 256, 0, stream>>>(XMh, XMt);   // XMh dead after
  tr16_kernel<<<trgrid, 256, 0, stream>>>(xh, Xt);     // xh dead after

  zero_kernel<<<(B_DIM * SPEC_ST + 255) / 256, 256, 0, stream>>>(spec, B_DIM * SPEC_ST);
  twiddle_kernel<<<4, 256, 0, stream>>>(twg);

  fft_corr_kernel<<<B_DIM * (C_DIM / CG), 256, 0, stream>>>(XMt, Xt, twg, spec);
  ifft_topk_kernel<<<B_DIM, 256, 0, stream>>>(spec, twg, wgt, dly);

  aggregate_kernel<<<(T_LEN * C_DIM / 8 / 256) * B_DIM, 256, 0, stream>>>(V, wgt, dly, V2);

  wt3_kernel<<<tgrid, 256, 0, stream>>>(Wp, Wp, Wp, Wpt, Wpt, Wpt);  // z=0 slice only

  // out = V2 @ Wpt + bp -> d_out f32 (spec/twg/XMt dead)
  gemm_f16_kernel<1><<<pgrid, 256, 0, stream>>>(V2, Wpt, bp, d_out, C_DIM, C_DIM);
}

// Round 7
// 502.930 us; speedup vs baseline: 1.3283x; 1.0047x over previous
//
#include <hip/hip_runtime.h>

// Problem constants (B,T,C,H,E = 8,2048,1024,16,64; TOP_K=38)
#define T_LEN 2048
#define B_DIM 8
#define C_DIM 1024
#define TOPK  38
#define FFT_N 2048
#define SPEC_ST 2050   // floats per batch: 1025 complex (k=0..1024)

typedef _Float16 half8 __attribute__((ext_vector_type(8)));
typedef float  floatx4 __attribute__((ext_vector_type(4)));
typedef unsigned int u32;

__device__ __forceinline__ void async16(const void* g, void* l) {
  __builtin_amdgcn_global_load_lds(
      (const __attribute__((address_space(1))) u32*)g,
      (__attribute__((address_space(3))) u32*)l, 16, 0, 0);
}

__device__ __forceinline__ int rev11(int x) { return (int)(__brev((u32)x) >> 21); }
// LDS bank swizzle (bijective): XOR high addr bits into bank field.
__device__ __forceinline__ int SW(int a) { return a ^ ((a >> 5) & 31); }

struct cpx { float r, i; };
__device__ __forceinline__ cpx csqr(cpx a) { return {a.r*a.r - a.i*a.i, 2.0f*a.r*a.i}; }
// multiply by W^(256*m) = e^{-i pi m/4}
__device__ __forceinline__ cpx c8m(cpx a, int m) {
  const float R2 = 0.70710678118654752f;
  switch (m & 3) {
    case 0:  return a;
    case 1:  return {R2*(a.r + a.i), R2*(a.i - a.r)};
    case 2:  return {a.i, -a.r};
    default: return {R2*(a.i - a.r), -R2*(a.r + a.i)};
  }
}

// Three DIF stages (distances 4,2,1 in units of the ownership stride) on 8
// register-resident points. tb = W^(lane_sub * tstep_of_first_stage).
__device__ __forceinline__ void radix8(float zr[8], float zi[8], cpx tb) {
  cpx tb2 = csqr(tb), tb4 = csqr(tb2);
  #pragma unroll
  for (int m = 0; m < 4; ++m) {
    cpx tw = c8m(tb, m);
    float ur = zr[m], ui = zi[m], vr = zr[m+4], vi = zi[m+4];
    zr[m] = ur + vr; zi[m] = ui + vi;
    float sr = ur - vr, si = ui - vi;
    zr[m+4] = sr*tw.r - si*tw.i; zi[m+4] = sr*tw.i + si*tw.r;
  }
  cpx twb = c8m(tb2, 2);
  #pragma unroll
  for (int h = 0; h < 2; ++h) {
    int b0 = h * 4;
    { cpx tw = tb2;
      float ur = zr[b0], ui = zi[b0], vr = zr[b0+2], vi = zi[b0+2];
      zr[b0] = ur + vr; zi[b0] = ui + vi;
      float sr = ur - vr, si = ui - vi;
      zr[b0+2] = sr*tw.r - si*tw.i; zi[b0+2] = sr*tw.i + si*tw.r; }
    { cpx tw = twb;
      float ur = zr[b0+1], ui = zi[b0+1], vr = zr[b0+3], vi = zi[b0+3];
      zr[b0+1] = ur + vr; zi[b0+1] = ui + vi;
      float sr = ur - vr, si = ui - vi;
      zr[b0+3] = sr*tw.r - si*tw.i; zi[b0+3] = sr*tw.i + si*tw.r; }
  }
  #pragma unroll
  for (int p = 0; p < 8; p += 2) {
    float ur = zr[p], ui = zi[p], vr = zr[p+1], vi = zi[p+1];
    zr[p] = ur + vr; zi[p] = ui + vi;
    float sr = ur - vr, si = ui - vi;
    zr[p+1] = sr*tb4.r - si*tb4.i; zi[p+1] = sr*tb4.i + si*tb4.r;
  }
}

// ---------------------------------------------------------------- spec zero + twiddle init
__global__ __launch_bounds__(256) void init_kernel(
    float* __restrict__ spec, int n, float* __restrict__ twg) {
  int i = blockIdx.x * 256 + threadIdx.x;
  if (i < n) spec[i] = 0.0f;
  if (i < FFT_N / 2) {
    float th = -3.14159265358979323846f * (float)i / 1024.0f;
    twg[2 * i]     = cosf(th);
    twg[2 * i + 1] = sinf(th);
  }
}

// ---------------------------------------------------------------- f32 -> fp16 (8/thread)
__global__ __launch_bounds__(256) void cvt_f16_kernel(
    const float* __restrict__ src, _Float16* __restrict__ dst, int n8) {
  int i = blockIdx.x * 256 + threadIdx.x;
  if (i >= n8) return;
  floatx4 a = ((const floatx4*)src)[i * 2];
  floatx4 b = ((const floatx4*)src)[i * 2 + 1];
  half8 o;
  #pragma unroll
  for (int j = 0; j < 4; ++j) { o[j] = (_Float16)a[j]; o[j + 4] = (_Float16)b[j]; }
  ((half8*)dst)[i] = o;
}

// ---------------------------------------------------------------- W [K,N] f32 -> Wt [N,K] fp16 (batched x3)
__global__ __launch_bounds__(256) void wt3_kernel(
    const float* __restrict__ w0, const float* __restrict__ w1,
    const float* __restrict__ w2, _Float16* __restrict__ d0,
    _Float16* __restrict__ d1, _Float16* __restrict__ d2) {
  const float* src = blockIdx.z == 0 ? w0 : (blockIdx.z == 1 ? w1 : w2);
  _Float16*    dst = blockIdx.z == 0 ? d0 : (blockIdx.z == 1 ? d1 : d2);
  __shared__ _Float16 tile[64][65];
  int k0 = blockIdx.y * 64, n0 = blockIdx.x * 64;
  int tx = threadIdx.x & 63, ty = threadIdx.x >> 6;  // ty 0..3
  #pragma unroll
  for (int j = 0; j < 16; ++j) {
    int r = j * 4 + ty;
    tile[r][tx] = (_Float16)src[(size_t)(k0 + r) * C_DIM + n0 + tx];
  }
  __syncthreads();
  #pragma unroll
  for (int j = 0; j < 16; ++j) {
    int r = j * 4 + ty;
    dst[(size_t)(n0 + r) * C_DIM + k0 + tx] = tile[tx][r];
  }
}

// ---------------------------------------------------------------- fp16 [B][T][C] -> [B][C][T] transpose
__global__ __launch_bounds__(256) void tr16_kernel(
    const _Float16* __restrict__ src, _Float16* __restrict__ dst) {
  __shared__ _Float16 tile[64][65];
  int b = blockIdx.z;
  int t0 = blockIdx.x * 64, c0 = blockIdx.y * 64;
  const _Float16* s = src + (size_t)b * T_LEN * C_DIM;
  _Float16* d = dst + (size_t)b * C_DIM * T_LEN;
  int tid = threadIdx.x;
  int c8 = (tid & 7) * 8, tr = tid >> 3;          // tr 0..31
  #pragma unroll
  for (int h = 0; h < 2; ++h) {
    int r = tr + h * 32;
    half8 v = *(const half8*)&s[(size_t)(t0 + r) * C_DIM + c0 + c8];
    #pragma unroll
    for (int j = 0; j < 8; ++j) tile[r][c8 + j] = v[j];
  }
  __syncthreads();
  int t8 = (tid & 7) * 8, cr = tid >> 3;
  #pragma unroll
  for (int h = 0; h < 2; ++h) {
    int c = cr + h * 32;
    half8 o;
    #pragma unroll
    for (int j = 0; j < 8; ++j) o[j] = tile[t8 + j][c];
    *(half8*)&d[(size_t)(c0 + c) * T_LEN + t0 + t8] = o;
  }
}

// ---------------------------------------------------------------- per-channel FFT cross-spectrum
// Register-resident radix-8 DIF: 2048 = 8*8*8*4. Thread owns 8 points.
// Base twiddles read directly from global (3 complex per thread; L2-resident) --
// no twiddle LDS (24->16 KB) so more blocks fit; CG=4 doubles grid for residency.
// Batch XCD-pinned: b = blockIdx&7.
#define CG 4
__global__ __launch_bounds__(256) void fft_corr_kernel(
    const _Float16* __restrict__ XMt, const _Float16* __restrict__ Xt,
    const float* __restrict__ twg, float* __restrict__ spec) {
  __shared__ float re[FFT_N], im[FFT_N];
  const int tid = threadIdx.x;
  const int b = blockIdx.x & 7;                  // XCD-pinned batch
  const int cg0 = (blockIdx.x >> 3) * CG;        // 256 chan-groups per batch
  const int lo5 = tid & 31, blk = tid >> 5;
  const int lo2 = tid & 3,  g   = tid >> 2;
  const _Float16* xmB = XMt + (size_t)b * C_DIM * T_LEN;
  const _Float16* xB  = Xt  + (size_t)b * C_DIM * T_LEN;
  float sRa[4] = {0.f, 0.f, 0.f, 0.f};
  float sIa[4] = {0.f, 0.f, 0.f, 0.f};
  float s1024 = 0.f;
  float zr[8], zi[8], nr[8], ni[8];
  // prefetch channel 0 (stride-256 ownership: per-instr 64 consecutive fp16)
  #pragma unroll
  for (int m = 0; m < 8; ++m) {
    nr[m] = (float)xmB[(size_t)cg0 * T_LEN + tid + 256 * m];
    ni[m] = (float)xB [(size_t)cg0 * T_LEN + tid + 256 * m];
  }
  cpx tA = {twg[2 * tid],            twg[2 * tid + 1]};        // W^tid
  cpx tB = {twg[2 * (8 * lo5)],      twg[2 * (8 * lo5) + 1]};  // W^(8 lo5)
  cpx tC = {twg[2 * (64 * lo2)],     twg[2 * (64 * lo2) + 1]}; // W^(64 lo2)
  for (int cc = 0; cc < CG; ++cc) {
    #pragma unroll
    for (int m = 0; m < 8; ++m) { zr[m] = nr[m]; zi[m] = ni[m]; }
    if (cc + 1 < CG) {
      const size_t off = (size_t)(cg0 + cc + 1) * T_LEN;
      #pragma unroll
      for (int m = 0; m < 8; ++m) {
        nr[m] = (float)xmB[off + tid + 256 * m];
        ni[m] = (float)xB [off + tid + 256 * m];
      }
    }
    radix8(zr, zi, tA);                          // stages 0-2
    __syncthreads();                             // prev separation reads done
    #pragma unroll
    for (int m = 0; m < 8; ++m) { int a = SW(tid + 256 * m); re[a] = zr[m]; im[a] = zi[m]; }
    __syncthreads();
    #pragma unroll
    for (int m = 0; m < 8; ++m) { int a = SW(256 * blk + 32 * m + lo5); zr[m] = re[a]; zi[m] = im[a]; }
    radix8(zr, zi, tB);                          // stages 3-5
    __syncthreads();                             // all ex1 reads done
    #pragma unroll
    for (int m = 0; m < 8; ++m) { int a = SW(256 * blk + 32 * m + lo5); re[a] = zr[m]; im[a] = zi[m]; }
    __syncthreads();
    #pragma unroll
    for (int m = 0; m < 8; ++m) { int a = SW(32 * g + 4 * m + lo2); zr[m] = re[a]; zi[m] = im[a]; }
    radix8(zr, zi, tC);                          // stages 6-8
    // stage 9: distance 2 -> lanes tid^2; upper twiddle W^(512*(tid&1))
    #pragma unroll
    for (int m = 0; m < 8; ++m) {
      float pr = __shfl_xor(zr[m], 2), pi = __shfl_xor(zi[m], 2);
      if ((tid & 2) == 0) { zr[m] += pr; zi[m] += pi; }
      else {
        float sr = pr - zr[m], si = pi - zi[m];
        if (tid & 1) { zr[m] = si; zi[m] = -sr; }   // *( -i )
        else         { zr[m] = sr; zi[m] = si; }
      }
    }
    // stage 10: distance 1 -> lanes tid^1; twiddle 1
    #pragma unroll
    for (int m = 0; m < 8; ++m) {
      float pr = __shfl_xor(zr[m], 1), pi = __shfl_xor(zi[m], 1);
      if ((tid & 1) == 0) { zr[m] += pr; zi[m] += pi; }
      else                { zr[m] = pr - zr[m]; zi[m] = pi - zi[m]; }
    }
    __syncthreads();                             // all ex2 reads done
    #pragma unroll
    for (int m = 0; m < 8; ++m) { int a = SW(32 * g + 4 * m + lo2); re[a] = zr[m]; im[a] = zi[m]; }
    __syncthreads();
    // separation + register accumulation (k = tid + 256r) -- verified r5 code
    #pragma unroll
    for (int r = 0; r < 4; ++r) {
      int k = tid + r * 256;
      if (k == 0) {
        sRa[0] += re[0] * im[0];                  // S[0]    (Z[0] at pos 0)
        s1024  += re[1] * im[1];                  // S[1024] (Z[1024] at pos rev=1)
      } else {
        int pk = SW(rev11(k)), pn = SW(rev11(FFT_N - k));
        float zr_ = re[pk], zi_ = im[pk], yr = re[pn], yi = im[pn];
        float ar = 0.5f * (zr_ + yr), ai = 0.5f * (zi_ - yi);   // XMf[k]
        float br = 0.5f * (zi_ + yi), bi = -0.5f * (zr_ - yr);  // Xf[k]
        sRa[r] += ar * br + ai * bi;              // Re(XMf*conj(Xf))
        sIa[r] += ai * br - ar * bi;              // Im
      }
    }
  }
  float* sb = spec + (size_t)b * SPEC_ST;
  #pragma unroll
  for (int r = 0; r < 4; ++r) {
    int k = tid + r * 256;
    atomicAdd(&sb[2 * k],     sRa[r]);
    atomicAdd(&sb[2 * k + 1], sIa[r]);
  }
  if (tid == 0) atomicAdd(&sb[2048], s1024);
}

// ---------------------------------------------------------------- inverse FFT + top-k + softmax
__global__ __launch_bounds__(256) void ifft_topk_kernel(
    const float* __restrict__ spec, const float* __restrict__ twg,
    float* __restrict__ wgt, int* __restrict__ dly) {
  __shared__ float re[FFT_N], im[FFT_N];
  __shared__ float twr[FFT_N / 2], twi[FFT_N / 2];
  __shared__ float vals[FFT_N];
  __shared__ float swv[4];
  __shared__ int   swidx[4];
  __shared__ float selw[TOPK];
  __shared__ int   seli[TOPK];
  int b = blockIdx.x, tid = threadIdx.x;
  for (int i = tid; i < FFT_N / 2; i += 256) { twr[SW(i)] = twg[2 * i]; twi[SW(i)] = twg[2 * i + 1]; }
  const float* sb = spec + (size_t)b * SPEC_ST;
  for (int i = tid; i < FFT_N; i += 256) {
    int src = (i <= 1024) ? i : (FFT_N - i);
    float sgn = (i <= 1024) ? 1.0f : -1.0f;
    re[SW(i)] = sb[2 * src];
    im[SW(i)] = sgn * sb[2 * src + 1];
  }
  __syncthreads();
  #pragma unroll 1
  for (int s = 0; s < 11; ++s) {
    const int half = 1024 >> s, tstep = 1 << s;
    #pragma unroll
    for (int r = 0; r < 4; ++r) {
      int idx = tid + r * 256;
      int j = idx & (half - 1);
      int i0 = SW(2 * idx - j), i1 = SW(2 * idx - j + half);
      float ur = re[i0], ui = im[i0], vr = re[i1], vi = im[i1];
      float sr = ur - vr, si = ui - vi;
      int tix = SW(j * tstep);
      float wr = twr[tix], wi = twi[tix];
      re[i0] = ur + vr; im[i0] = ui + vi;
      re[i1] = sr * wr + si * wi;          // (sr+i si)*conj(w)
      im[i1] = si * wr - sr * wi;
    }
    __syncthreads();
  }
  const float sc = 1.0f / 2097152.0f;      // 1/2048 (IDFT) * 1/1024 (channel mean)
  for (int i = tid; i < FFT_N; i += 256) vals[SW(rev11(i))] = re[SW(i)] * sc;
  __syncthreads();
  for (int it = 0; it < TOPK; ++it) {
    float bv = -3.4e38f; int bi = T_LEN - 1;
    for (int i = tid; i < T_LEN; i += 256) {
      float v = vals[SW(i)];
      if (v > bv || (v == bv && i < bi)) { bv = v; bi = i; }
    }
    #pragma unroll
    for (int off = 32; off > 0; off >>= 1) {
      float ov = __shfl_down(bv, off);
      int   oi = __shfl_down(bi, off);
      if (ov > bv || (ov == bv && oi < bi)) { bv = ov; bi = oi; }
    }
    if ((tid & 63) == 0) { swv[tid >> 6] = bv; swidx[tid >> 6] = bi; }
    __syncthreads();
    if (tid == 0) {
      #pragma unroll
      for (int ww = 1; ww < 4; ++ww) {
        float ov = swv[ww]; int oi = swidx[ww];
        if (ov > bv || (ov == bv && oi < bi)) { bv = ov; bi = oi; }
      }
      if (bi < 0) bi = 0; if (bi > T_LEN - 1) bi = T_LEN - 1;
      selw[it] = bv; seli[it] = bi;
      vals[SW(bi)] = -3.4e38f;
    }
    __syncthreads();
  }
  if (tid == 0) {
    float m = selw[0], s = 0.0f, e[TOPK];
    for (int i = 0; i < TOPK; ++i) { e[i] = expf(selw[i] - m); s += e[i]; }
    float inv = 1.0f / s;
    for (int i = 0; i < TOPK; ++i) { wgt[b * TOPK + i] = e[i] * inv; dly[b * TOPK + i] = seli[i]; }
  }
}

// ---------------------------------------------------------------- fp16 NT GEMM (m97-style + read swizzle)
// C[m,n] = sum_k A[m*K+k]*B[n*K+k]; EPI: 0 = fp16 store + bias, 1 = f32 store + bias.
// blockIdx.z selects (B,bias,out) pair so independent same-A GEMMs share a dispatch.
template <int EPI>
__global__ __launch_bounds__(256, 3) void gemm_f16_kernel(
    const _Float16* __restrict__ A, const _Float16* __restrict__ B,
    const float* __restrict__ bias, void* __restrict__ outv, int N, int K,
    const _Float16* __restrict__ B2, const float* __restrict__ bias2,
    void* __restrict__ outv2) {
  __shared__ __align__(16) _Float16 lA[128 * 64];
  __shared__ __align__(16) _Float16 lB[128 * 64];

  if (blockIdx.z) { B = B2; bias = bias2; outv = outv2; }

  const int tid = threadIdx.x;
  const int bm = blockIdx.x, bn = blockIdx.y;
  const int lane = tid & 63, w = tid >> 6;
  const int wm = w >> 1, wn = w & 1;     // 2x2 waves -> 64x64 tiles
  const int lr = lane & 15, lg = lane >> 4;

  const int lrow = lane >> 3;            // 0..7 = row within 8-row slab
  const int lcol = (((lane & 7) ^ lrow) * 8);

  const _Float16* pA[4];
  const _Float16* pB[4];
  _Float16* dA[4];
  _Float16* dB[4];
  #pragma unroll
  for (int j = 0; j < 4; ++j) {
    int r = w * 32 + j * 8;
    pA[j] = A + (long long)(bm * 128 + r + lrow) * K + lcol;
    pB[j] = B + (long long)(bn * 128 + r + lrow) * K + lcol;
    dA[j] = &lA[r * 64];
    dB[j] = &lB[r * 64];
  }

  const int coff = (((lr >> 2) & 1) * 32) | ((lg ^ (lr & 3)) * 8);

  floatx4 acc[4][4];
  #pragma unroll
  for (int i = 0; i < 4; ++i)
    #pragma unroll
    for (int j = 0; j < 4; ++j) { acc[i][j][0]=0.f; acc[i][j][1]=0.f; acc[i][j][2]=0.f; acc[i][j][3]=0.f; }

  const int nk = K >> 6;
  for (int kt = 0; kt < nk; ++kt) {
    __syncthreads();
    #pragma unroll
    for (int j = 0; j < 4; ++j) {
      async16(pA[j], dA[j]);
      async16(pB[j], dB[j]);
      pA[j] += 64; pB[j] += 64;
    }
    __syncthreads();
    #pragma unroll
    for (int s = 0; s < 2; ++s) {
      const int so = coff ^ (s * 32);
      half8 af[4], bf[4];
      #pragma unroll
      for (int mi = 0; mi < 4; ++mi)
        af[mi] = *(const half8*)&lA[(wm * 64 + mi * 16 + lr) * 64 + so];
      #pragma unroll
      for (int ni = 0; ni < 4; ++ni)
        bf[ni] = *(const half8*)&lB[(wn * 64 + ni * 16 + lr) * 64 + so];
      #pragma unroll
      for (int mi = 0; mi < 4; ++mi)
        #pragma unroll
        for (int ni = 0; ni < 4; ++ni)
          acc[mi][ni] = __builtin_amdgcn_mfma_f32_16x16x32_f16(
              af[mi], bf[ni], acc[mi][ni], 0, 0, 0);
    }
  }

  float bvs[4];
  #pragma unroll
  for (int ni = 0; ni < 4; ++ni) {
    int gc = bn * 128 + wn * 64 + ni * 16 + lr;
    bvs[ni] = bias ? bias[gc & (C_DIM - 1)] : 0.0f;
  }
  #pragma unroll
  for (int mi = 0; mi < 4; ++mi)
    #pragma unroll
    for (int ni = 0; ni < 4; ++ni) {
      int gc = bn * 128 + wn * 64 + ni * 16 + lr;
      #pragma unroll
      for (int i = 0; i < 4; ++i) {
        int gr = bm * 128 + wm * 64 + mi * 16 + lg * 4 + i;
        float v = acc[mi][ni][i] + bvs[ni];
        long long idx = (long long)gr * N + gc;
        if constexpr (EPI == 1) ((float*)outv)[idx] = v;
        else                    ((_Float16*)outv)[idx] = (_Float16)v;
      }
    }
}

// ---------------------------------------------------------------- aggregation (+reference's reshape)
__global__ __launch_bounds__(256) void aggregate_kernel(
    const _Float16* __restrict__ V, const float* __restrict__ wgt,
    const int* __restrict__ dly, _Float16* __restrict__ V2) {
  int b = blockIdx.x & 7;                         // batch pinned to XCD
  int g = (blockIdx.x >> 3) * 256 + threadIdx.x;  // 0 .. T*C/8-1
  int c8 = g & 127;
  int tp = g >> 7;
  int h = tp >> 7, lhi = tp & 127;
  int cp = c8 << 3;
  int e0 = cp & 63, lo = cp >> 6;
  int l = lhi * 16 + lo;
  int ch = h * 64 + e0;
  float acc[8];
  #pragma unroll
  for (int j = 0; j < 8; ++j) acc[j] = 0.0f;
  const long long vbase = (long long)b * T_LEN * C_DIM;
  for (int k = 0; k < TOPK; ++k) {
    float w = wgt[b * TOPK + k];
    int d = dly[b * TOPK + k];
    int ts = (l + d) & (T_LEN - 1);
    half8 vv = *(const half8*)(V + vbase + (long long)ts * C_DIM + ch);
    #pragma unroll
    for (int j = 0; j < 8; ++j) acc[j] += w * (float)vv[j];
  }
  half8 o;
  #pragma unroll
  for (int j = 0; j < 8; ++j) o[j] = (_Float16)acc[j];
  __builtin_nontemporal_store(o, (half8*)(V2 + vbase + (long long)tp * C_DIM + cp));
}

// ---------------------------------------------------------------- launcher
extern "C" void kernel_launch(void* const* d_in, const int* in_sizes, int n_in,
                              void* d_out, int out_size, void* d_ws, size_t ws_size,
                              hipStream_t stream) {
  const float* x  = (const float*)d_in[0];
  const float* Wq = (const float*)d_in[1];
  const float* Wk = (const float*)d_in[3];
  const float* Wv = (const float*)d_in[5];
  const float* bv = (const float*)d_in[6];
  const float* Wp = (const float*)d_in[7];
  const float* bp = (const float*)d_in[8];
  // bq/bk provably irrelevant (constant shift of corr; top-k order & softmax shift-invariant)

  // corr path: Q.K^T == X (Wq Wk^T) X^T; corr[l] = sum_c circcorr(XM_c, x_c)[l]
  //            computed in O(N log N) per channel via FFT cross-spectrum.
  // d_out (64 MiB):
  //   [0,32M)  xh fp16 (live until Xt transpose) -> then spec(66K)+twg(8K)
  //   [32,64M) Wqh/Wkh/Wvt/Mt2 (2M each, dead after XM & V GEMMs) -> then XMt (32M)
  // ws (>= 64MiB + 72KiB proven):
  //   [0,32M)  XMh -> Xt -> V2      [32,64M) V -> Wpt      tail: wgt, dly
  const size_t SZ_H = (size_t)B_DIM * T_LEN * C_DIM * 2;   // 32 MiB
  const size_t NEEDED = 2 * SZ_H + 65536 + 8192;
  if (ws_size < NEEDED) return;

  char* ws = (char*)d_ws;
  _Float16* XMh = (_Float16*)ws;
  _Float16* V   = (_Float16*)(ws + SZ_H);
  float* wgt   = (float*)(ws + 2 * SZ_H + 65536);
  int*   dly   = (int*)(ws + 2 * SZ_H + 65536 + 4096);
  _Float16* Xt  = (_Float16*)ws;             // after XM transpose (XMh dead)
  _Float16* V2  = (_Float16*)ws;             // after fft_corr (Xt dead)
  _Float16* Wpt = (_Float16*)(ws + SZ_H);    // after agg (V dead), 2 MiB

  char* dob = (char*)d_out;
  _Float16* xh  = (_Float16*)dob;
  float*    spec = (float*)dob;                        // after xh dead: 66 KiB
  float*    twg  = (float*)(dob + 131072);             // 8 KiB
  _Float16* Wqh = (_Float16*)(dob + 32 * 1048576);
  _Float16* Wkh = (_Float16*)(dob + 34 * 1048576);
  _Float16* Wvt = (_Float16*)(dob + 36 * 1048576);
  _Float16* Mt2 = (_Float16*)(dob + 38 * 1048576);
  _Float16* XMt = (_Float16*)(dob + 32 * 1048576);     // after weights dead: 32 MiB

  const int M = B_DIM * T_LEN;  // 16384

  cvt_f16_kernel<<<(M * C_DIM / 8) / 256, 256, 0, stream>>>(x, xh, M * C_DIM / 8);
  cvt_f16_kernel<<<(C_DIM * C_DIM / 8) / 256, 256, 0, stream>>>(Wq, Wqh, C_DIM * C_DIM / 8);
  cvt_f16_kernel<<<(C_DIM * C_DIM / 8) / 256, 256, 0, stream>>>(Wk, Wkh, C_DIM * C_DIM / 8);

  dim3 tgrid(16, 16, 1);
  wt3_kernel<<<tgrid, 256, 0, stream>>>(Wv, Wv, Wv, Wvt, Wvt, Wvt);   // z=0 slice only

  dim3 pgrid2(M / 128, C_DIM / 128, 2);       // (128, 8, 2) dual GEMM
  dim3 pgrid(M / 128, C_DIM / 128, 1);        // (128, 8)
  dim3 mgrid(C_DIM / 128, C_DIM / 128, 1);    // (8, 8)

  // Mt2[m,n] = sum_o Wk[m,o] * Wq[n,o]
  gemm_f16_kernel<0><<<mgrid, 256, 0, stream>>>(Wkh, Wqh, nullptr, Mt2, C_DIM, C_DIM,
                                                nullptr, nullptr, nullptr);
  // z=0: XM[t,c] = sum_a x[t,a] * Mt2[c,a];  z=1: V = xh @ Wvt + bv
  gemm_f16_kernel<0><<<pgrid2, 256, 0, stream>>>(xh, Mt2, nullptr, XMh, C_DIM, C_DIM,
                                                 Wvt, bv, V);

  dim3 trgrid(T_LEN / 64, C_DIM / 64, B_DIM); // (32, 16, 8)
  tr16_kernel<<<trgrid, 256, 0, stream>>>(XMh, XMt);   // XMh dead after
  tr16_kernel<<<trgrid, 256, 0, stream>>>(xh, Xt);     // xh dead after

  init_kernel<<<(B_DIM * SPEC_ST + 255) / 256, 256, 0, stream>>>(spec, B_DIM * SPEC_ST, twg);

  fft_corr_kernel<<<B_DIM * (C_DIM / CG), 256, 0, stream>>>(XMt, Xt, twg, spec);
  ifft_topk_kernel<<<B_DIM, 256, 0, stream>>>(spec, twg, wgt, dly);

  aggregate_kernel<<<(T_LEN * C_DIM / 8 / 256) * B_DIM, 256, 0, stream>>>(V, wgt, dly, V2);

  wt3_kernel<<<tgrid, 256, 0, stream>>>(Wp, Wp, Wp, Wpt, Wpt, Wpt);  // z=0 slice only

  // out = V2 @ Wpt + bp -> d_out f32 (spec/twg/XMt dead)
  gemm_f16_kernel<1><<<pgrid, 256, 0, stream>>>(V2, Wpt, bp, d_out, C_DIM, C_DIM,
                                                nullptr, nullptr, nullptr);
}

// Round 8
// 485.289 us; speedup vs baseline: 1.3765x; 1.0364x over previous
//
#include <hip/hip_runtime.h>

// Problem constants (B,T,C,H,E = 8,2048,1024,16,64; TOP_K=38)
#define T_LEN 2048
#define B_DIM 8
#define C_DIM 1024
#define TOPK  38
#define FFT_N 2048
#define SPEC_ST 2050   // floats per batch: 1025 complex (k=0..1024)

typedef _Float16 half8 __attribute__((ext_vector_type(8)));
typedef _Float16 half4 __attribute__((ext_vector_type(4)));
typedef float  floatx4 __attribute__((ext_vector_type(4)));
typedef unsigned int u32;

__device__ __forceinline__ void async16(const void* g, void* l) {
  __builtin_amdgcn_global_load_lds(
      (const __attribute__((address_space(1))) u32*)g,
      (__attribute__((address_space(3))) u32*)l, 16, 0, 0);
}

__device__ __forceinline__ int rev11(int x) { return (int)(__brev((u32)x) >> 21); }
// LDS bank swizzle (bijective): XOR high addr bits into bank field.
__device__ __forceinline__ int SW(int a) { return a ^ ((a >> 5) & 31); }

struct cpx { float r, i; };
__device__ __forceinline__ cpx csqr(cpx a) { return {a.r*a.r - a.i*a.i, 2.0f*a.r*a.i}; }
// multiply by W^(256*m) = e^{-i pi m/4}
__device__ __forceinline__ cpx c8m(cpx a, int m) {
  const float R2 = 0.70710678118654752f;
  switch (m & 3) {
    case 0:  return a;
    case 1:  return {R2*(a.r + a.i), R2*(a.i - a.r)};
    case 2:  return {a.i, -a.r};
    default: return {R2*(a.i - a.r), -R2*(a.r + a.i)};
  }
}

// Three DIF stages (distances 4,2,1 in units of the ownership stride) on 8
// register-resident points. tb = W^(lane_sub * tstep_of_first_stage).
__device__ __forceinline__ void radix8(float zr[8], float zi[8], cpx tb) {
  cpx tb2 = csqr(tb), tb4 = csqr(tb2);
  #pragma unroll
  for (int m = 0; m < 4; ++m) {
    cpx tw = c8m(tb, m);
    float ur = zr[m], ui = zi[m], vr = zr[m+4], vi = zi[m+4];
    zr[m] = ur + vr; zi[m] = ui + vi;
    float sr = ur - vr, si = ui - vi;
    zr[m+4] = sr*tw.r - si*tw.i; zi[m+4] = sr*tw.i + si*tw.r;
  }
  cpx twb = c8m(tb2, 2);
  #pragma unroll
  for (int h = 0; h < 2; ++h) {
    int b0 = h * 4;
    { cpx tw = tb2;
      float ur = zr[b0], ui = zi[b0], vr = zr[b0+2], vi = zi[b0+2];
      zr[b0] = ur + vr; zi[b0] = ui + vi;
      float sr = ur - vr, si = ui - vi;
      zr[b0+2] = sr*tw.r - si*tw.i; zi[b0+2] = sr*tw.i + si*tw.r; }
    { cpx tw = twb;
      float ur = zr[b0+1], ui = zi[b0+1], vr = zr[b0+3], vi = zi[b0+3];
      zr[b0+1] = ur + vr; zi[b0+1] = ui + vi;
      float sr = ur - vr, si = ui - vi;
      zr[b0+3] = sr*tw.r - si*tw.i; zi[b0+3] = sr*tw.i + si*tw.r; }
  }
  #pragma unroll
  for (int p = 0; p < 8; p += 2) {
    float ur = zr[p], ui = zi[p], vr = zr[p+1], vi = zi[p+1];
    zr[p] = ur + vr; zi[p] = ui + vi;
    float sr = ur - vr, si = ui - vi;
    zr[p+1] = sr*tb4.r - si*tb4.i; zi[p+1] = sr*tb4.i + si*tb4.r;
  }
}

// ---------------------------------------------------------------- spec zero + twiddle init
__global__ __launch_bounds__(256) void init_kernel(
    float* __restrict__ spec, int n, float* __restrict__ twg) {
  int i = blockIdx.x * 256 + threadIdx.x;
  if (i < n) spec[i] = 0.0f;
  if (i < FFT_N / 2) {
    float th = -3.14159265358979323846f * (float)i / 1024.0f;
    twg[2 * i]     = cosf(th);
    twg[2 * i + 1] = sinf(th);
  }
}

// ---------------------------------------------------------------- f32 -> fp16 (8/thread)
__global__ __launch_bounds__(256) void cvt_f16_kernel(
    const float* __restrict__ src, _Float16* __restrict__ dst, int n8) {
  int i = blockIdx.x * 256 + threadIdx.x;
  if (i >= n8) return;
  floatx4 a = ((const floatx4*)src)[i * 2];
  floatx4 b = ((const floatx4*)src)[i * 2 + 1];
  half8 o;
  #pragma unroll
  for (int j = 0; j < 4; ++j) { o[j] = (_Float16)a[j]; o[j + 4] = (_Float16)b[j]; }
  ((half8*)dst)[i] = o;
}

// ---------------------------------------------------------------- W [K,N] f32 -> Wt [N,K] fp16 (batched x3)
__global__ __launch_bounds__(256) void wt3_kernel(
    const float* __restrict__ w0, const float* __restrict__ w1,
    const float* __restrict__ w2, _Float16* __restrict__ d0,
    _Float16* __restrict__ d1, _Float16* __restrict__ d2) {
  const float* src = blockIdx.z == 0 ? w0 : (blockIdx.z == 1 ? w1 : w2);
  _Float16*    dst = blockIdx.z == 0 ? d0 : (blockIdx.z == 1 ? d1 : d2);
  __shared__ _Float16 tile[64][65];
  int k0 = blockIdx.y * 64, n0 = blockIdx.x * 64;
  int tx = threadIdx.x & 63, ty = threadIdx.x >> 6;  // ty 0..3
  #pragma unroll
  for (int j = 0; j < 16; ++j) {
    int r = j * 4 + ty;
    tile[r][tx] = (_Float16)src[(size_t)(k0 + r) * C_DIM + n0 + tx];
  }
  __syncthreads();
  #pragma unroll
  for (int j = 0; j < 16; ++j) {
    int r = j * 4 + ty;
    dst[(size_t)(n0 + r) * C_DIM + k0 + tx] = tile[tx][r];
  }
}

// ---------------------------------------------------------------- fp16 [B][T][C] -> [B][C][T] transpose
__global__ __launch_bounds__(256) void tr16_kernel(
    const _Float16* __restrict__ src, _Float16* __restrict__ dst) {
  __shared__ _Float16 tile[64][65];
  int b = blockIdx.z;
  int t0 = blockIdx.x * 64, c0 = blockIdx.y * 64;
  const _Float16* s = src + (size_t)b * T_LEN * C_DIM;
  _Float16* d = dst + (size_t)b * C_DIM * T_LEN;
  int tid = threadIdx.x;
  int c8 = (tid & 7) * 8, tr = tid >> 3;          // tr 0..31
  #pragma unroll
  for (int h = 0; h < 2; ++h) {
    int r = tr + h * 32;
    half8 v = *(const half8*)&s[(size_t)(t0 + r) * C_DIM + c0 + c8];
    #pragma unroll
    for (int j = 0; j < 8; ++j) tile[r][c8 + j] = v[j];
  }
  __syncthreads();
  int t8 = (tid & 7) * 8, cr = tid >> 3;
  #pragma unroll
  for (int h = 0; h < 2; ++h) {
    int c = cr + h * 32;
    half8 o;
    #pragma unroll
    for (int j = 0; j < 8; ++j) o[j] = tile[t8 + j][c];
    *(half8*)&d[(size_t)(c0 + c) * T_LEN + t0 + t8] = o;
  }
}

// ---------------------------------------------------------------- per-channel FFT cross-spectrum
// Register-resident radix-8 DIF: 2048 = 8*8*8*4. Thread owns 8 points.
// Complex packed as float2 -> every LDS exchange/separation access is ONE
// ds_{read,write}_b64 (48 instr/thread/channel vs 112 b32): the r7 PMC showed
// the kernel is LDS-instruction-throughput-bound (35 us pipe + 12 us conflicts).
// b64 natural rate is 16 lanes/clk via bank pairs; SW keeps addresses <=2-way
// mod 16 so no new conflict class.
#define CG 4
__global__ __launch_bounds__(256) void fft_corr_kernel(
    const _Float16* __restrict__ XMt, const _Float16* __restrict__ Xt,
    const float* __restrict__ twg, float* __restrict__ spec) {
  __shared__ float2 zc[FFT_N];                   // 16 KB
  const int tid = threadIdx.x;
  const int b = blockIdx.x & 7;                  // XCD-pinned batch
  const int cg0 = (blockIdx.x >> 3) * CG;        // 256 chan-groups per batch
  const int lo5 = tid & 31, blk = tid >> 5;
  const int lo2 = tid & 3,  g   = tid >> 2;
  const _Float16* xmB = XMt + (size_t)b * C_DIM * T_LEN;
  const _Float16* xB  = Xt  + (size_t)b * C_DIM * T_LEN;
  float sRa[4] = {0.f, 0.f, 0.f, 0.f};
  float sIa[4] = {0.f, 0.f, 0.f, 0.f};
  float s1024 = 0.f;
  float zr[8], zi[8], nr[8], ni[8];
  // prefetch channel 0 (stride-256 ownership: per-instr 64 consecutive fp16)
  #pragma unroll
  for (int m = 0; m < 8; ++m) {
    nr[m] = (float)xmB[(size_t)cg0 * T_LEN + tid + 256 * m];
    ni[m] = (float)xB [(size_t)cg0 * T_LEN + tid + 256 * m];
  }
  cpx tA = {twg[2 * tid],            twg[2 * tid + 1]};        // W^tid
  cpx tB = {twg[2 * (8 * lo5)],      twg[2 * (8 * lo5) + 1]};  // W^(8 lo5)
  cpx tC = {twg[2 * (64 * lo2)],     twg[2 * (64 * lo2) + 1]}; // W^(64 lo2)
  for (int cc = 0; cc < CG; ++cc) {
    #pragma unroll
    for (int m = 0; m < 8; ++m) { zr[m] = nr[m]; zi[m] = ni[m]; }
    if (cc + 1 < CG) {
      const size_t off = (size_t)(cg0 + cc + 1) * T_LEN;
      #pragma unroll
      for (int m = 0; m < 8; ++m) {
        nr[m] = (float)xmB[off + tid + 256 * m];
        ni[m] = (float)xB [off + tid + 256 * m];
      }
    }
    radix8(zr, zi, tA);                          // stages 0-2
    __syncthreads();                             // prev separation reads done
    #pragma unroll
    for (int m = 0; m < 8; ++m) { int a = SW(tid + 256 * m); zc[a] = make_float2(zr[m], zi[m]); }
    __syncthreads();
    #pragma unroll
    for (int m = 0; m < 8; ++m) { float2 v = zc[SW(256 * blk + 32 * m + lo5)]; zr[m] = v.x; zi[m] = v.y; }
    radix8(zr, zi, tB);                          // stages 3-5
    __syncthreads();                             // all ex1 reads done
    #pragma unroll
    for (int m = 0; m < 8; ++m) { int a = SW(256 * blk + 32 * m + lo5); zc[a] = make_float2(zr[m], zi[m]); }
    __syncthreads();
    #pragma unroll
    for (int m = 0; m < 8; ++m) { float2 v = zc[SW(32 * g + 4 * m + lo2)]; zr[m] = v.x; zi[m] = v.y; }
    radix8(zr, zi, tC);                          // stages 6-8
    // stage 9: distance 2 -> lanes tid^2; upper twiddle W^(512*(tid&1))
    #pragma unroll
    for (int m = 0; m < 8; ++m) {
      float pr = __shfl_xor(zr[m], 2), pi = __shfl_xor(zi[m], 2);
      if ((tid & 2) == 0) { zr[m] += pr; zi[m] += pi; }
      else {
        float sr = pr - zr[m], si = pi - zi[m];
        if (tid & 1) { zr[m] = si; zi[m] = -sr; }   // *( -i )
        else         { zr[m] = sr; zi[m] = si; }
      }
    }
    // stage 10: distance 1 -> lanes tid^1; twiddle 1
    #pragma unroll
    for (int m = 0; m < 8; ++m) {
      float pr = __shfl_xor(zr[m], 1), pi = __shfl_xor(zi[m], 1);
      if ((tid & 1) == 0) { zr[m] += pr; zi[m] += pi; }
      else                { zr[m] = pr - zr[m]; zi[m] = pi - zi[m]; }
    }
    __syncthreads();                             // all ex2 reads done
    #pragma unroll
    for (int m = 0; m < 8; ++m) { int a = SW(32 * g + 4 * m + lo2); zc[a] = make_float2(zr[m], zi[m]); }
    __syncthreads();
    // separation + register accumulation (k = tid + 256r)
    #pragma unroll
    for (int r = 0; r < 4; ++r) {
      int k = tid + r * 256;
      if (k == 0) {
        float2 z0 = zc[SW(0)], z1 = zc[SW(1)];
        sRa[0] += z0.x * z0.y;                    // S[0]    (Z[0] at pos 0)
        s1024  += z1.x * z1.y;                    // S[1024] (Z[1024] at pos rev=1)
      } else {
        float2 zk = zc[SW(rev11(k))], zn = zc[SW(rev11(FFT_N - k))];
        float ar = 0.5f * (zk.x + zn.x), ai = 0.5f * (zk.y - zn.y);   // XMf[k]
        float br = 0.5f * (zk.y + zn.y), bi = -0.5f * (zk.x - zn.x);  // Xf[k]
        sRa[r] += ar * br + ai * bi;              // Re(XMf*conj(Xf))
        sIa[r] += ai * br - ar * bi;              // Im
      }
    }
  }
  float* sb = spec + (size_t)b * SPEC_ST;
  #pragma unroll
  for (int r = 0; r < 4; ++r) {
    int k = tid + r * 256;
    atomicAdd(&sb[2 * k],     sRa[r]);
    atomicAdd(&sb[2 * k + 1], sIa[r]);
  }
  if (tid == 0) atomicAdd(&sb[2048], s1024);
}

// ---------------------------------------------------------------- inverse FFT + top-k + softmax
__global__ __launch_bounds__(256) void ifft_topk_kernel(
    const float* __restrict__ spec, const float* __restrict__ twg,
    float* __restrict__ wgt, int* __restrict__ dly) {
  __shared__ float re[FFT_N], im[FFT_N];
  __shared__ float twr[FFT_N / 2], twi[FFT_N / 2];
  __shared__ float vals[FFT_N];
  __shared__ float swv[4];
  __shared__ int   swidx[4];
  __shared__ float selw[TOPK];
  __shared__ int   seli[TOPK];
  int b = blockIdx.x, tid = threadIdx.x;
  for (int i = tid; i < FFT_N / 2; i += 256) { twr[SW(i)] = twg[2 * i]; twi[SW(i)] = twg[2 * i + 1]; }
  const float* sb = spec + (size_t)b * SPEC_ST;
  for (int i = tid; i < FFT_N; i += 256) {
    int src = (i <= 1024) ? i : (FFT_N - i);
    float sgn = (i <= 1024) ? 1.0f : -1.0f;
    re[SW(i)] = sb[2 * src];
    im[SW(i)] = sgn * sb[2 * src + 1];
  }
  __syncthreads();
  #pragma unroll 1
  for (int s = 0; s < 11; ++s) {
    const int half = 1024 >> s, tstep = 1 << s;
    #pragma unroll
    for (int r = 0; r < 4; ++r) {
      int idx = tid + r * 256;
      int j = idx & (half - 1);
      int i0 = SW(2 * idx - j), i1 = SW(2 * idx - j + half);
      float ur = re[i0], ui = im[i0], vr = re[i1], vi = im[i1];
      float sr = ur - vr, si = ui - vi;
      int tix = SW(j * tstep);
      float wr = twr[tix], wi = twi[tix];
      re[i0] = ur + vr; im[i0] = ui + vi;
      re[i1] = sr * wr + si * wi;          // (sr+i si)*conj(w)
      im[i1] = si * wr - sr * wi;
    }
    __syncthreads();
  }
  const float sc = 1.0f / 2097152.0f;      // 1/2048 (IDFT) * 1/1024 (channel mean)
  for (int i = tid; i < FFT_N; i += 256) vals[SW(rev11(i))] = re[SW(i)] * sc;
  __syncthreads();
  for (int it = 0; it < TOPK; ++it) {
    float bv = -3.4e38f; int bi = T_LEN - 1;
    for (int i = tid; i < T_LEN; i += 256) {
      float v = vals[SW(i)];
      if (v > bv || (v == bv && i < bi)) { bv = v; bi = i; }
    }
    #pragma unroll
    for (int off = 32; off > 0; off >>= 1) {
      float ov = __shfl_down(bv, off);
      int   oi = __shfl_down(bi, off);
      if (ov > bv || (ov == bv && oi < bi)) { bv = ov; bi = oi; }
    }
    if ((tid & 63) == 0) { swv[tid >> 6] = bv; swidx[tid >> 6] = bi; }
    __syncthreads();
    if (tid == 0) {
      #pragma unroll
      for (int ww = 1; ww < 4; ++ww) {
        float ov = swv[ww]; int oi = swidx[ww];
        if (ov > bv || (ov == bv && oi < bi)) { bv = ov; bi = oi; }
      }
      if (bi < 0) bi = 0; if (bi > T_LEN - 1) bi = T_LEN - 1;
      selw[it] = bv; seli[it] = bi;
      vals[SW(bi)] = -3.4e38f;
    }
    __syncthreads();
  }
  if (tid == 0) {
    float m = selw[0], s = 0.0f, e[TOPK];
    for (int i = 0; i < TOPK; ++i) { e[i] = expf(selw[i] - m); s += e[i]; }
    float inv = 1.0f / s;
    for (int i = 0; i < TOPK; ++i) { wgt[b * TOPK + i] = e[i] * inv; dly[b * TOPK + i] = seli[i]; }
  }
}

// ---------------------------------------------------------------- fp16 NT GEMM (m97-style + read swizzle)
// C[m,n] = sum_k A[m*K+k]*B[n*K+k].
// EPI: 0 = fp16 store + bias; 1 = f32 store + bias;
//      2 = dual: z0 -> TRANSPOSED fp16 store into [B][C][T] (fuses the XM
//          transpose: acc's i-index is 4 consecutive t -> one half4 store),
//          z1 -> normal fp16 + bias.
template <int EPI>
__global__ __launch_bounds__(256, 3) void gemm_f16_kernel(
    const _Float16* __restrict__ A, const _Float16* __restrict__ B,
    const float* __restrict__ bias, void* __restrict__ outv, int N, int K,
    const _Float16* __restrict__ B2, const float* __restrict__ bias2,
    void* __restrict__ outv2) {
  __shared__ __align__(16) _Float16 lA[128 * 64];
  __shared__ __align__(16) _Float16 lB[128 * 64];

  if (blockIdx.z) { B = B2; bias = bias2; outv = outv2; }

  const int tid = threadIdx.x;
  const int bm = blockIdx.x, bn = blockIdx.y;
  const int lane = tid & 63, w = tid >> 6;
  const int wm = w >> 1, wn = w & 1;     // 2x2 waves -> 64x64 tiles
  const int lr = lane & 15, lg = lane >> 4;

  const int lrow = lane >> 3;            // 0..7 = row within 8-row slab
  const int lcol = (((lane & 7) ^ lrow) * 8);

  const _Float16* pA[4];
  const _Float16* pB[4];
  _Float16* dA[4];
  _Float16* dB[4];
  #pragma unroll
  for (int j = 0; j < 4; ++j) {
    int r = w * 32 + j * 8;
    pA[j] = A + (long long)(bm * 128 + r + lrow) * K + lcol;
    pB[j] = B + (long long)(bn * 128 + r + lrow) * K + lcol;
    dA[j] = &lA[r * 64];
    dB[j] = &lB[r * 64];
  }

  const int coff = (((lr >> 2) & 1) * 32) | ((lg ^ (lr & 3)) * 8);

  floatx4 acc[4][4];
  #pragma unroll
  for (int i = 0; i < 4; ++i)
    #pragma unroll
    for (int j = 0; j < 4; ++j) { acc[i][j][0]=0.f; acc[i][j][1]=0.f; acc[i][j][2]=0.f; acc[i][j][3]=0.f; }

  const int nk = K >> 6;
  for (int kt = 0; kt < nk; ++kt) {
    __syncthreads();
    #pragma unroll
    for (int j = 0; j < 4; ++j) {
      async16(pA[j], dA[j]);
      async16(pB[j], dB[j]);
      pA[j] += 64; pB[j] += 64;
    }
    __syncthreads();
    #pragma unroll
    for (int s = 0; s < 2; ++s) {
      const int so = coff ^ (s * 32);
      half8 af[4], bf[4];
      #pragma unroll
      for (int mi = 0; mi < 4; ++mi)
        af[mi] = *(const half8*)&lA[(wm * 64 + mi * 16 + lr) * 64 + so];
      #pragma unroll
      for (int ni = 0; ni < 4; ++ni)
        bf[ni] = *(const half8*)&lB[(wn * 64 + ni * 16 + lr) * 64 + so];
      #pragma unroll
      for (int mi = 0; mi < 4; ++mi)
        #pragma unroll
        for (int ni = 0; ni < 4; ++ni)
          acc[mi][ni] = __builtin_amdgcn_mfma_f32_16x16x32_f16(
              af[mi], bf[ni], acc[mi][ni], 0, 0, 0);
    }
  }

  if (EPI == 2 && blockIdx.z == 0) {
    // transposed store: out[b][c][t], 4 consecutive t per fragment
    #pragma unroll
    for (int mi = 0; mi < 4; ++mi)
      #pragma unroll
      for (int ni = 0; ni < 4; ++ni) {
        int gc  = bn * 128 + wn * 64 + ni * 16 + lr;
        int gr0 = bm * 128 + wm * 64 + mi * 16 + lg * 4;
        int bb = gr0 >> 11, t0 = gr0 & (T_LEN - 1);
        half4 o;
        #pragma unroll
        for (int i = 0; i < 4; ++i) o[i] = (_Float16)acc[mi][ni][i];
        *(half4*)&(((_Float16*)outv)[((size_t)bb * C_DIM + gc) * T_LEN + t0]) = o;
      }
    return;
  }

  float bvs[4];
  #pragma unroll
  for (int ni = 0; ni < 4; ++ni) {
    int gc = bn * 128 + wn * 64 + ni * 16 + lr;
    bvs[ni] = bias ? bias[gc & (C_DIM - 1)] : 0.0f;
  }
  #pragma unroll
  for (int mi = 0; mi < 4; ++mi)
    #pragma unroll
    for (int ni = 0; ni < 4; ++ni) {
      int gc = bn * 128 + wn * 64 + ni * 16 + lr;
      #pragma unroll
      for (int i = 0; i < 4; ++i) {
        int gr = bm * 128 + wm * 64 + mi * 16 + lg * 4 + i;
        float v = acc[mi][ni][i] + bvs[ni];
        long long idx = (long long)gr * N + gc;
        if constexpr (EPI == 1) ((float*)outv)[idx] = v;
        else                    ((_Float16*)outv)[idx] = (_Float16)v;
      }
    }
}

// ---------------------------------------------------------------- aggregation (+reference's reshape)
__global__ __launch_bounds__(256) void aggregate_kernel(
    const _Float16* __restrict__ V, const float* __restrict__ wgt,
    const int* __restrict__ dly, _Float16* __restrict__ V2) {
  int b = blockIdx.x & 7;                         // batch pinned to XCD
  int g = (blockIdx.x >> 3) * 256 + threadIdx.x;  // 0 .. T*C/8-1
  int c8 = g & 127;
  int tp = g >> 7;
  int h = tp >> 7, lhi = tp & 127;
  int cp = c8 << 3;
  int e0 = cp & 63, lo = cp >> 6;
  int l = lhi * 16 + lo;
  int ch = h * 64 + e0;
  float acc[8];
  #pragma unroll
  for (int j = 0; j < 8; ++j) acc[j] = 0.0f;
  const long long vbase = (long long)b * T_LEN * C_DIM;
  for (int k = 0; k < TOPK; ++k) {
    float w = wgt[b * TOPK + k];
    int d = dly[b * TOPK + k];
    int ts = (l + d) & (T_LEN - 1);
    half8 vv = *(const half8*)(V + vbase + (long long)ts * C_DIM + ch);
    #pragma unroll
    for (int j = 0; j < 8; ++j) acc[j] += w * (float)vv[j];
  }
  half8 o;
  #pragma unroll
  for (int j = 0; j < 8; ++j) o[j] = (_Float16)acc[j];
  __builtin_nontemporal_store(o, (half8*)(V2 + vbase + (long long)tp * C_DIM + cp));
}

// ---------------------------------------------------------------- launcher
extern "C" void kernel_launch(void* const* d_in, const int* in_sizes, int n_in,
                              void* d_out, int out_size, void* d_ws, size_t ws_size,
                              hipStream_t stream) {
  const float* x  = (const float*)d_in[0];
  const float* Wq = (const float*)d_in[1];
  const float* Wk = (const float*)d_in[3];
  const float* Wv = (const float*)d_in[5];
  const float* bv = (const float*)d_in[6];
  const float* Wp = (const float*)d_in[7];
  const float* bp = (const float*)d_in[8];
  // bq/bk provably irrelevant (constant shift of corr; top-k order & softmax shift-invariant)

  // corr path: Q.K^T == X (Wq Wk^T) X^T; corr[l] = sum_c circcorr(XM_c, x_c)[l]
  //            via per-channel FFT cross-spectrum.
  // ws (>= 64MiB + 72KiB proven):
  //   [0,32M)  XMt (dual GEMM z0, transposed epi) -> V2 after fft
  //   [32,64M) V  -> Wpt after aggregate          tail: wgt, dly
  // d_out (64 MiB):
  //   [0,32M)  xh fp16 (live until tr16) -> then spec(66K)+twg(8K) -> final out
  //   [32,64M) Wqh/Wkh/Wvt/Mt2 (dead after dual GEMM) -> then Xt (32M)
  const size_t SZ_H = (size_t)B_DIM * T_LEN * C_DIM * 2;   // 32 MiB
  const size_t NEEDED = 2 * SZ_H + 65536 + 8192;
  if (ws_size < NEEDED) return;

  char* ws = (char*)d_ws;
  _Float16* XMt = (_Float16*)ws;
  _Float16* V   = (_Float16*)(ws + SZ_H);
  float* wgt   = (float*)(ws + 2 * SZ_H + 65536);
  int*   dly   = (int*)(ws + 2 * SZ_H + 65536 + 4096);
  _Float16* V2  = (_Float16*)ws;             // after fft_corr (XMt dead)
  _Float16* Wpt = (_Float16*)(ws + SZ_H);    // after agg (V dead), 2 MiB

  char* dob = (char*)d_out;
  _Float16* xh  = (_Float16*)dob;
  float*    spec = (float*)dob;                        // after xh dead: 66 KiB
  float*    twg  = (float*)(dob + 131072);             // 8 KiB
  _Float16* Wqh = (_Float16*)(dob + 32 * 1048576);
  _Float16* Wkh = (_Float16*)(dob + 34 * 1048576);
  _Float16* Wvt = (_Float16*)(dob + 36 * 1048576);
  _Float16* Mt2 = (_Float16*)(dob + 38 * 1048576);
  _Float16* Xt  = (_Float16*)(dob + 32 * 1048576);     // after weights dead: 32 MiB

  const int M = B_DIM * T_LEN;  // 16384

  cvt_f16_kernel<<<(M * C_DIM / 8) / 256, 256, 0, stream>>>(x, xh, M * C_DIM / 8);
  cvt_f16_kernel<<<(C_DIM * C_DIM / 8) / 256, 256, 0, stream>>>(Wq, Wqh, C_DIM * C_DIM / 8);
  cvt_f16_kernel<<<(C_DIM * C_DIM / 8) / 256, 256, 0, stream>>>(Wk, Wkh, C_DIM * C_DIM / 8);

  dim3 tgrid(16, 16, 1);
  wt3_kernel<<<tgrid, 256, 0, stream>>>(Wv, Wv, Wv, Wvt, Wvt, Wvt);   // z=0 slice only

  dim3 pgrid2(M / 128, C_DIM / 128, 2);       // (128, 8, 2) dual GEMM
  dim3 pgrid(M / 128, C_DIM / 128, 1);        // (128, 8)
  dim3 mgrid(C_DIM / 128, C_DIM / 128, 1);    // (8, 8)

  // Mt2[m,n] = sum_o Wk[m,o] * Wq[n,o]
  gemm_f16_kernel<0><<<mgrid, 256, 0, stream>>>(Wkh, Wqh, nullptr, Mt2, C_DIM, C_DIM,
                                                nullptr, nullptr, nullptr);
  // z=0: XMt[b][c][t] = sum_a x[t,a]*Mt2[c,a] (transposed epi);  z=1: V = xh@Wvt + bv
  gemm_f16_kernel<2><<<pgrid2, 256, 0, stream>>>(xh, Mt2, nullptr, XMt, C_DIM, C_DIM,
                                                 Wvt, bv, V);

  dim3 trgrid(T_LEN / 64, C_DIM / 64, B_DIM); // (32, 16, 8)
  tr16_kernel<<<trgrid, 256, 0, stream>>>(xh, Xt);     // xh dead after (weights dead too)

  init_kernel<<<(B_DIM * SPEC_ST + 255) / 256, 256, 0, stream>>>(spec, B_DIM * SPEC_ST, twg);

  fft_corr_kernel<<<B_DIM * (C_DIM / CG), 256, 0, stream>>>(XMt, Xt, twg, spec);
  ifft_topk_kernel<<<B_DIM, 256, 0, stream>>>(spec, twg, wgt, dly);

  aggregate_kernel<<<(T_LEN * C_DIM / 8 / 256) * B_DIM, 256, 0, stream>>>(V, wgt, dly, V2);

  wt3_kernel<<<tgrid, 256, 0, stream>>>(Wp, Wp, Wp, Wpt, Wpt, Wpt);  // z=0 slice only

  // out = V2 @ Wpt + bp -> d_out f32 (spec/twg/Xt dead)
  gemm_f16_kernel<1><<<pgrid, 256, 0, stream>>>(V2, Wpt, bp, d_out, C_DIM, C_DIM,
                                                nullptr, nullptr, nullptr);
}

// Round 9
// 472.742 us; speedup vs baseline: 1.4131x; 1.0265x over previous
//
#include <hip/hip_runtime.h>

// Problem constants (B,T,C,H,E = 8,2048,1024,16,64; TOP_K=38)
#define T_LEN 2048
#define B_DIM 8
#define C_DIM 1024
#define TOPK  38
#define FFT_N 2048
#define SPEC_ST 2050   // floats per batch: 1025 complex (k=0..1024)

typedef _Float16 half8 __attribute__((ext_vector_type(8)));
typedef _Float16 half4 __attribute__((ext_vector_type(4)));
typedef float  floatx4 __attribute__((ext_vector_type(4)));
typedef unsigned int u32;

__device__ __forceinline__ void async16(const void* g, void* l) {
  __builtin_amdgcn_global_load_lds(
      (const __attribute__((address_space(1))) u32*)g,
      (__attribute__((address_space(3))) u32*)l, 16, 0, 0);
}

__device__ __forceinline__ int rev11(int x) { return (int)(__brev((u32)x) >> 21); }
// LDS bank swizzle (bijective): XOR high addr bits into bank field.
__device__ __forceinline__ int SW(int a) { return a ^ ((a >> 5) & 31); }

struct cpx { float r, i; };
__device__ __forceinline__ cpx csqr(cpx a) { return {a.r*a.r - a.i*a.i, 2.0f*a.r*a.i}; }
// multiply by W^(256*m) = e^{-i pi m/4}
__device__ __forceinline__ cpx c8m(cpx a, int m) {
  const float R2 = 0.70710678118654752f;
  switch (m & 3) {
    case 0:  return a;
    case 1:  return {R2*(a.r + a.i), R2*(a.i - a.r)};
    case 2:  return {a.i, -a.r};
    default: return {R2*(a.i - a.r), -R2*(a.r + a.i)};
  }
}

// Three DIF stages (distances 4,2,1 in units of the ownership stride) on 8
// register-resident points. tb = W^(lane_sub * tstep_of_first_stage).
__device__ __forceinline__ void radix8(float zr[8], float zi[8], cpx tb) {
  cpx tb2 = csqr(tb), tb4 = csqr(tb2);
  #pragma unroll
  for (int m = 0; m < 4; ++m) {
    cpx tw = c8m(tb, m);
    float ur = zr[m], ui = zi[m], vr = zr[m+4], vi = zi[m+4];
    zr[m] = ur + vr; zi[m] = ui + vi;
    float sr = ur - vr, si = ui - vi;
    zr[m+4] = sr*tw.r - si*tw.i; zi[m+4] = sr*tw.i + si*tw.r;
  }
  cpx twb = c8m(tb2, 2);
  #pragma unroll
  for (int h = 0; h < 2; ++h) {
    int b0 = h * 4;
    { cpx tw = tb2;
      float ur = zr[b0], ui = zi[b0], vr = zr[b0+2], vi = zi[b0+2];
      zr[b0] = ur + vr; zi[b0] = ui + vi;
      float sr = ur - vr, si = ui - vi;
      zr[b0+2] = sr*tw.r - si*tw.i; zi[b0+2] = sr*tw.i + si*tw.r; }
    { cpx tw = twb;
      float ur = zr[b0+1], ui = zi[b0+1], vr = zr[b0+3], vi = zi[b0+3];
      zr[b0+1] = ur + vr; zi[b0+1] = ui + vi;
      float sr = ur - vr, si = ui - vi;
      zr[b0+3] = sr*tw.r - si*tw.i; zi[b0+3] = sr*tw.i + si*tw.r; }
  }
  #pragma unroll
  for (int p = 0; p < 8; p += 2) {
    float ur = zr[p], ui = zi[p], vr = zr[p+1], vi = zi[p+1];
    zr[p] = ur + vr; zi[p] = ui + vi;
    float sr = ur - vr, si = ui - vi;
    zr[p+1] = sr*tb4.r - si*tb4.i; zi[p+1] = sr*tb4.i + si*tb4.r;
  }
}

// ---------------------------------------------------------------- spec zero + twiddle init
__global__ __launch_bounds__(256) void init_kernel(
    float* __restrict__ spec, int n, float* __restrict__ twg) {
  int i = blockIdx.x * 256 + threadIdx.x;
  if (i < n) spec[i] = 0.0f;
  if (i < FFT_N / 2) {
    float th = -3.14159265358979323846f * (float)i / 1024.0f;
    twg[2 * i]     = cosf(th);
    twg[2 * i + 1] = sinf(th);
  }
}

// ---------------------------------------------------------------- f32 -> fp16 (8/thread)
__global__ __launch_bounds__(256) void cvt_f16_kernel(
    const float* __restrict__ src, _Float16* __restrict__ dst, int n8) {
  int i = blockIdx.x * 256 + threadIdx.x;
  if (i >= n8) return;
  floatx4 a = ((const floatx4*)src)[i * 2];
  floatx4 b = ((const floatx4*)src)[i * 2 + 1];
  half8 o;
  #pragma unroll
  for (int j = 0; j < 4; ++j) { o[j] = (_Float16)a[j]; o[j + 4] = (_Float16)b[j]; }
  ((half8*)dst)[i] = o;
}

// ---------------------------------------------------------------- W [K,N] f32 -> Wt [N,K] fp16 (batched x3)
__global__ __launch_bounds__(256) void wt3_kernel(
    const float* __restrict__ w0, const float* __restrict__ w1,
    const float* __restrict__ w2, _Float16* __restrict__ d0,
    _Float16* __restrict__ d1, _Float16* __restrict__ d2) {
  const float* src = blockIdx.z == 0 ? w0 : (blockIdx.z == 1 ? w1 : w2);
  _Float16*    dst = blockIdx.z == 0 ? d0 : (blockIdx.z == 1 ? d1 : d2);
  __shared__ _Float16 tile[64][65];
  int k0 = blockIdx.y * 64, n0 = blockIdx.x * 64;
  int tx = threadIdx.x & 63, ty = threadIdx.x >> 6;  // ty 0..3
  #pragma unroll
  for (int j = 0; j < 16; ++j) {
    int r = j * 4 + ty;
    tile[r][tx] = (_Float16)src[(size_t)(k0 + r) * C_DIM + n0 + tx];
  }
  __syncthreads();
  #pragma unroll
  for (int j = 0; j < 16; ++j) {
    int r = j * 4 + ty;
    dst[(size_t)(n0 + r) * C_DIM + k0 + tx] = tile[tx][r];
  }
}

// ---------------------------------------------------------------- fp16 [B][T][C] -> [B][C][T] transpose
__global__ __launch_bounds__(256) void tr16_kernel(
    const _Float16* __restrict__ src, _Float16* __restrict__ dst) {
  __shared__ _Float16 tile[64][65];
  int b = blockIdx.z;
  int t0 = blockIdx.x * 64, c0 = blockIdx.y * 64;
  const _Float16* s = src + (size_t)b * T_LEN * C_DIM;
  _Float16* d = dst + (size_t)b * C_DIM * T_LEN;
  int tid = threadIdx.x;
  int c8 = (tid & 7) * 8, tr = tid >> 3;          // tr 0..31
  #pragma unroll
  for (int h = 0; h < 2; ++h) {
    int r = tr + h * 32;
    half8 v = *(const half8*)&s[(size_t)(t0 + r) * C_DIM + c0 + c8];
    #pragma unroll
    for (int j = 0; j < 8; ++j) tile[r][c8 + j] = v[j];
  }
  __syncthreads();
  int t8 = (tid & 7) * 8, cr = tid >> 3;
  #pragma unroll
  for (int h = 0; h < 2; ++h) {
    int c = cr + h * 32;
    half8 o;
    #pragma unroll
    for (int j = 0; j < 8; ++j) o[j] = tile[t8 + j][c];
    *(half8*)&d[(size_t)(c0 + c) * T_LEN + t0 + t8] = o;
  }
}

// ---------------------------------------------------------------- per-channel FFT cross-spectrum
// Register-resident radix-8 DIF; complex packed float2 (b64 LDS ops).
#define CG 4
__global__ __launch_bounds__(256) void fft_corr_kernel(
    const _Float16* __restrict__ XMt, const _Float16* __restrict__ Xt,
    const float* __restrict__ twg, float* __restrict__ spec) {
  __shared__ float2 zc[FFT_N];                   // 16 KB
  const int tid = threadIdx.x;
  const int b = blockIdx.x & 7;                  // XCD-pinned batch
  const int cg0 = (blockIdx.x >> 3) * CG;        // 256 chan-groups per batch
  const int lo5 = tid & 31, blk = tid >> 5;
  const int lo2 = tid & 3,  g   = tid >> 2;
  const _Float16* xmB = XMt + (size_t)b * C_DIM * T_LEN;
  const _Float16* xB  = Xt  + (size_t)b * C_DIM * T_LEN;
  float sRa[4] = {0.f, 0.f, 0.f, 0.f};
  float sIa[4] = {0.f, 0.f, 0.f, 0.f};
  float s1024 = 0.f;
  float zr[8], zi[8], nr[8], ni[8];
  #pragma unroll
  for (int m = 0; m < 8; ++m) {
    nr[m] = (float)xmB[(size_t)cg0 * T_LEN + tid + 256 * m];
    ni[m] = (float)xB [(size_t)cg0 * T_LEN + tid + 256 * m];
  }
  cpx tA = {twg[2 * tid],            twg[2 * tid + 1]};        // W^tid
  cpx tB = {twg[2 * (8 * lo5)],      twg[2 * (8 * lo5) + 1]};  // W^(8 lo5)
  cpx tC = {twg[2 * (64 * lo2)],     twg[2 * (64 * lo2) + 1]}; // W^(64 lo2)
  for (int cc = 0; cc < CG; ++cc) {
    #pragma unroll
    for (int m = 0; m < 8; ++m) { zr[m] = nr[m]; zi[m] = ni[m]; }
    if (cc + 1 < CG) {
      const size_t off = (size_t)(cg0 + cc + 1) * T_LEN;
      #pragma unroll
      for (int m = 0; m < 8; ++m) {
        nr[m] = (float)xmB[off + tid + 256 * m];
        ni[m] = (float)xB [off + tid + 256 * m];
      }
    }
    radix8(zr, zi, tA);                          // stages 0-2
    __syncthreads();                             // prev separation reads done
    #pragma unroll
    for (int m = 0; m < 8; ++m) { int a = SW(tid + 256 * m); zc[a] = make_float2(zr[m], zi[m]); }
    __syncthreads();
    #pragma unroll
    for (int m = 0; m < 8; ++m) { float2 v = zc[SW(256 * blk + 32 * m + lo5)]; zr[m] = v.x; zi[m] = v.y; }
    radix8(zr, zi, tB);                          // stages 3-5
    __syncthreads();                             // all ex1 reads done
    #pragma unroll
    for (int m = 0; m < 8; ++m) { int a = SW(256 * blk + 32 * m + lo5); zc[a] = make_float2(zr[m], zi[m]); }
    __syncthreads();
    #pragma unroll
    for (int m = 0; m < 8; ++m) { float2 v = zc[SW(32 * g + 4 * m + lo2)]; zr[m] = v.x; zi[m] = v.y; }
    radix8(zr, zi, tC);                          // stages 6-8
    // stage 9: distance 2 -> lanes tid^2; upper twiddle W^(512*(tid&1))
    #pragma unroll
    for (int m = 0; m < 8; ++m) {
      float pr = __shfl_xor(zr[m], 2), pi = __shfl_xor(zi[m], 2);
      if ((tid & 2) == 0) { zr[m] += pr; zi[m] += pi; }
      else {
        float sr = pr - zr[m], si = pi - zi[m];
        if (tid & 1) { zr[m] = si; zi[m] = -sr; }   // *( -i )
        else         { zr[m] = sr; zi[m] = si; }
      }
    }
    // stage 10: distance 1 -> lanes tid^1; twiddle 1
    #pragma unroll
    for (int m = 0; m < 8; ++m) {
      float pr = __shfl_xor(zr[m], 1), pi = __shfl_xor(zi[m], 1);
      if ((tid & 1) == 0) { zr[m] += pr; zi[m] += pi; }
      else                { zr[m] = pr - zr[m]; zi[m] = pi - zi[m]; }
    }
    __syncthreads();                             // all ex2 reads done
    #pragma unroll
    for (int m = 0; m < 8; ++m) { int a = SW(32 * g + 4 * m + lo2); zc[a] = make_float2(zr[m], zi[m]); }
    __syncthreads();
    // separation + register accumulation (k = tid + 256r)
    #pragma unroll
    for (int r = 0; r < 4; ++r) {
      int k = tid + r * 256;
      if (k == 0) {
        float2 z0 = zc[SW(0)], z1 = zc[SW(1)];
        sRa[0] += z0.x * z0.y;                    // S[0]    (Z[0] at pos 0)
        s1024  += z1.x * z1.y;                    // S[1024] (Z[1024] at pos rev=1)
      } else {
        float2 zk = zc[SW(rev11(k))], zn = zc[SW(rev11(FFT_N - k))];
        float ar = 0.5f * (zk.x + zn.x), ai = 0.5f * (zk.y - zn.y);   // XMf[k]
        float br = 0.5f * (zk.y + zn.y), bi = -0.5f * (zk.x - zn.x);  // Xf[k]
        sRa[r] += ar * br + ai * bi;              // Re(XMf*conj(Xf))
        sIa[r] += ai * br - ar * bi;              // Im
      }
    }
  }
  float* sb = spec + (size_t)b * SPEC_ST;
  #pragma unroll
  for (int r = 0; r < 4; ++r) {
    int k = tid + r * 256;
    atomicAdd(&sb[2 * k],     sRa[r]);
    atomicAdd(&sb[2 * k + 1], sIa[r]);
  }
  if (tid == 0) atomicAdd(&sb[2048], s1024);
}

// ---------------------------------------------------------------- inverse FFT + top-k + softmax
__global__ __launch_bounds__(256) void ifft_topk_kernel(
    const float* __restrict__ spec, const float* __restrict__ twg,
    float* __restrict__ wgt, int* __restrict__ dly) {
  __shared__ float re[FFT_N], im[FFT_N];
  __shared__ float twr[FFT_N / 2], twi[FFT_N / 2];
  __shared__ float vals[FFT_N];
  __shared__ float swv[4];
  __shared__ int   swidx[4];
  __shared__ float selw[TOPK];
  __shared__ int   seli[TOPK];
  int b = blockIdx.x, tid = threadIdx.x;
  for (int i = tid; i < FFT_N / 2; i += 256) { twr[SW(i)] = twg[2 * i]; twi[SW(i)] = twg[2 * i + 1]; }
  const float* sb = spec + (size_t)b * SPEC_ST;
  for (int i = tid; i < FFT_N; i += 256) {
    int src = (i <= 1024) ? i : (FFT_N - i);
    float sgn = (i <= 1024) ? 1.0f : -1.0f;
    re[SW(i)] = sb[2 * src];
    im[SW(i)] = sgn * sb[2 * src + 1];
  }
  __syncthreads();
  #pragma unroll 1
  for (int s = 0; s < 11; ++s) {
    const int half = 1024 >> s, tstep = 1 << s;
    #pragma unroll
    for (int r = 0; r < 4; ++r) {
      int idx = tid + r * 256;
      int j = idx & (half - 1);
      int i0 = SW(2 * idx - j), i1 = SW(2 * idx - j + half);
      float ur = re[i0], ui = im[i0], vr = re[i1], vi = im[i1];
      float sr = ur - vr, si = ui - vi;
      int tix = SW(j * tstep);
      float wr = twr[tix], wi = twi[tix];
      re[i0] = ur + vr; im[i0] = ui + vi;
      re[i1] = sr * wr + si * wi;          // (sr+i si)*conj(w)
      im[i1] = si * wr - sr * wi;
    }
    __syncthreads();
  }
  const float sc = 1.0f / 2097152.0f;      // 1/2048 (IDFT) * 1/1024 (channel mean)
  for (int i = tid; i < FFT_N; i += 256) vals[SW(rev11(i))] = re[SW(i)] * sc;
  __syncthreads();
  for (int it = 0; it < TOPK; ++it) {
    float bv = -3.4e38f; int bi = T_LEN - 1;
    for (int i = tid; i < T_LEN; i += 256) {
      float v = vals[SW(i)];
      if (v > bv || (v == bv && i < bi)) { bv = v; bi = i; }
    }
    #pragma unroll
    for (int off = 32; off > 0; off >>= 1) {
      float ov = __shfl_down(bv, off);
      int   oi = __shfl_down(bi, off);
      if (ov > bv || (ov == bv && oi < bi)) { bv = ov; bi = oi; }
    }
    if ((tid & 63) == 0) { swv[tid >> 6] = bv; swidx[tid >> 6] = bi; }
    __syncthreads();
    if (tid == 0) {
      #pragma unroll
      for (int ww = 1; ww < 4; ++ww) {
        float ov = swv[ww]; int oi = swidx[ww];
        if (ov > bv || (ov == bv && oi < bi)) { bv = ov; bi = oi; }
      }
      if (bi < 0) bi = 0; if (bi > T_LEN - 1) bi = T_LEN - 1;
      selw[it] = bv; seli[it] = bi;
      vals[SW(bi)] = -3.4e38f;
    }
    __syncthreads();
  }
  if (tid == 0) {
    float m = selw[0], s = 0.0f, e[TOPK];
    for (int i = 0; i < TOPK; ++i) { e[i] = expf(selw[i] - m); s += e[i]; }
    float inv = 1.0f / s;
    for (int i = 0; i < TOPK; ++i) { wgt[b * TOPK + i] = e[i] * inv; dly[b * TOPK + i] = seli[i]; }
  }
}

// ---------------------------------------------------------------- 128^2 fp16 NT GEMM (kept for the small Mt2 GEMM)
__global__ __launch_bounds__(256, 3) void gemm128_kernel(
    const _Float16* __restrict__ A, const _Float16* __restrict__ B,
    _Float16* __restrict__ out, int N, int K) {
  __shared__ __align__(16) _Float16 lA[128 * 64];
  __shared__ __align__(16) _Float16 lB[128 * 64];
  const int tid = threadIdx.x;
  const int bm = blockIdx.x, bn = blockIdx.y;
  const int lane = tid & 63, w = tid >> 6;
  const int wm = w >> 1, wn = w & 1;
  const int lr = lane & 15, lg = lane >> 4;
  const int lrow = lane >> 3;
  const int lcol = (((lane & 7) ^ lrow) * 8);
  const _Float16* pA[4];
  const _Float16* pB[4];
  _Float16* dA[4];
  _Float16* dB[4];
  #pragma unroll
  for (int j = 0; j < 4; ++j) {
    int r = w * 32 + j * 8;
    pA[j] = A + (long long)(bm * 128 + r + lrow) * K + lcol;
    pB[j] = B + (long long)(bn * 128 + r + lrow) * K + lcol;
    dA[j] = &lA[r * 64];
    dB[j] = &lB[r * 64];
  }
  const int coff = (((lr >> 2) & 1) * 32) | ((lg ^ (lr & 3)) * 8);
  floatx4 acc[4][4];
  #pragma unroll
  for (int i = 0; i < 4; ++i)
    #pragma unroll
    for (int j = 0; j < 4; ++j) { acc[i][j][0]=0.f; acc[i][j][1]=0.f; acc[i][j][2]=0.f; acc[i][j][3]=0.f; }
  const int nk = K >> 6;
  for (int kt = 0; kt < nk; ++kt) {
    __syncthreads();
    #pragma unroll
    for (int j = 0; j < 4; ++j) {
      async16(pA[j], dA[j]);
      async16(pB[j], dB[j]);
      pA[j] += 64; pB[j] += 64;
    }
    __syncthreads();
    #pragma unroll
    for (int s = 0; s < 2; ++s) {
      const int so = coff ^ (s * 32);
      half8 af[4], bf[4];
      #pragma unroll
      for (int mi = 0; mi < 4; ++mi)
        af[mi] = *(const half8*)&lA[(wm * 64 + mi * 16 + lr) * 64 + so];
      #pragma unroll
      for (int ni = 0; ni < 4; ++ni)
        bf[ni] = *(const half8*)&lB[(wn * 64 + ni * 16 + lr) * 64 + so];
      #pragma unroll
      for (int mi = 0; mi < 4; ++mi)
        #pragma unroll
        for (int ni = 0; ni < 4; ++ni)
          acc[mi][ni] = __builtin_amdgcn_mfma_f32_16x16x32_f16(
              af[mi], bf[ni], acc[mi][ni], 0, 0, 0);
    }
  }
  #pragma unroll
  for (int mi = 0; mi < 4; ++mi)
    #pragma unroll
    for (int ni = 0; ni < 4; ++ni) {
      int gc = bn * 128 + wn * 64 + ni * 16 + lr;
      #pragma unroll
      for (int i = 0; i < 4; ++i) {
        int gr = bm * 128 + wm * 64 + mi * 16 + lg * 4 + i;
        out[(long long)gr * N + gc] = (_Float16)acc[mi][ni][i];
      }
    }
}

// ---------------------------------------------------------------- 256^2 fp16 NT GEMM, counted-vmcnt pipeline (T3-lite+T4+T5)
// 512 threads = 8 waves (2 Mrow x 4 Ncol), per-wave C = 128x64, acc[8][4].
// LDS: 2 buffers x (A 256x64 + B 256x64) fp16 = 128 KiB; 1 block/CU.
// Schedule per K-tile t: COMPUTE(buf) -> barrier (all reads done) ->
//   STAGE(buf, t+2) -> s_waitcnt vmcnt(8) (tile t+1's 8 loads/wave landed;
//   barrier makes it block-wide) -> barrier. vmcnt never 0 in steady state
//   (T4); tail uses vmcnt(0). Race audit: WAR on staged buffer closed by
//   barrier 1; RAW on next buffer closed by vmcnt(8)+barrier 2.
// EPI: 1 = f32 store + bias; 2 = dual: z0 transposed fp16 [B][C][T], z1 fp16+bias.
template <int EPI>
__global__ __launch_bounds__(512, 2) void gemm256_kernel(
    const _Float16* __restrict__ A, const _Float16* __restrict__ B,
    const float* __restrict__ bias, void* __restrict__ outv, int N, int K,
    const _Float16* __restrict__ B2, const float* __restrict__ bias2,
    void* __restrict__ outv2) {
  __shared__ __align__(16) _Float16 lds[2][2][256 * 64];   // 128 KiB

  if (blockIdx.z) { B = B2; bias = bias2; outv = outv2; }

  const int tid = threadIdx.x;
  const int bm = blockIdx.x, bn = blockIdx.y;
  const int lane = tid & 63, w = tid >> 6;       // 8 waves
  const int wr = w >> 2, wc = w & 3;
  const int lr = lane & 15, lg = lane >> 4;

  // staging: 4 A-loads + 4 B-loads per thread per K-tile (8 vm ops/wave)
  const int strow = tid >> 3;                    // 0..63
  const int stcol = ((tid & 7) ^ (strow & 7)) * 8;   // source chunk pre-swizzle
  const _Float16* gA = A + (long long)(bm * 256 + strow) * K + stcol;
  const _Float16* gB = B + (long long)(bn * 256 + strow) * K + stcol;
  const int wbase = (tid >> 6) * 8;              // wave-uniform LDS row base

  const int coff = (((lr >> 2) & 1) * 32) | ((lg ^ (lr & 3)) * 8);

  floatx4 acc[8][4];
  #pragma unroll
  for (int i = 0; i < 8; ++i)
    #pragma unroll
    for (int j = 0; j < 4; ++j) { acc[i][j][0]=0.f; acc[i][j][1]=0.f; acc[i][j][2]=0.f; acc[i][j][3]=0.f; }

  auto STAGE = [&](int buf, int kt) {
    const _Float16* sa = gA + (long long)kt * 64;
    const _Float16* sb = gB + (long long)kt * 64;
    _Float16* da = &lds[buf][0][wbase * 64];
    _Float16* db = &lds[buf][1][wbase * 64];
    #pragma unroll
    for (int j = 0; j < 4; ++j) {
      async16(sa + (long long)j * 64 * K, da + j * 64 * 64);
      async16(sb + (long long)j * 64 * K, db + j * 64 * 64);
    }
  };

  auto COMPUTE = [&](int buf) {
    const _Float16* la = &lds[buf][0][0];
    const _Float16* lb = &lds[buf][1][0];
    #pragma unroll
    for (int s = 0; s < 2; ++s) {
      const int so = coff ^ (s * 32);
      half8 bf[4];
      #pragma unroll
      for (int ni = 0; ni < 4; ++ni)
        bf[ni] = *(const half8*)&lb[(wc * 64 + ni * 16 + lr) * 64 + so];
      #pragma unroll
      for (int mh = 0; mh < 2; ++mh) {
        half8 af[4];
        #pragma unroll
        for (int q = 0; q < 4; ++q)
          af[q] = *(const half8*)&la[(wr * 128 + (mh * 4 + q) * 16 + lr) * 64 + so];
        __builtin_amdgcn_s_setprio(1);
        #pragma unroll
        for (int q = 0; q < 4; ++q)
          #pragma unroll
          for (int ni = 0; ni < 4; ++ni)
            acc[mh * 4 + q][ni] = __builtin_amdgcn_mfma_f32_16x16x32_f16(
                af[q], bf[ni], acc[mh * 4 + q][ni], 0, 0, 0);
        __builtin_amdgcn_s_setprio(0);
      }
    }
  };

  const int nt = K >> 6;                          // 16
  STAGE(0, 0);
  STAGE(1, 1);
  asm volatile("s_waitcnt vmcnt(8)" ::: "memory");  // tile 0 landed (per wave)
  __builtin_amdgcn_s_barrier();
  asm volatile("" ::: "memory");

  int cur = 0;
  for (int t = 0; t < nt; ++t) {
    COMPUTE(cur);
    asm volatile("" ::: "memory");
    __builtin_amdgcn_s_barrier();                 // all waves done reading buf cur
    asm volatile("" ::: "memory");
    if (t + 2 < nt) {
      STAGE(cur, t + 2);
      asm volatile("s_waitcnt vmcnt(8)" ::: "memory");  // tile t+1 landed
    } else {
      asm volatile("s_waitcnt vmcnt(0)" ::: "memory");  // tail drain
    }
    __builtin_amdgcn_s_barrier();                 // buf cur^1 ready block-wide
    asm volatile("" ::: "memory");
    cur ^= 1;
  }

  if (EPI == 2 && blockIdx.z == 0) {
    // transposed store: out[b][c][t], 4 consecutive t per fragment
    #pragma unroll
    for (int mi = 0; mi < 8; ++mi)
      #pragma unroll
      for (int ni = 0; ni < 4; ++ni) {
        int gc  = bn * 256 + wc * 64 + ni * 16 + lr;
        int gr0 = bm * 256 + wr * 128 + mi * 16 + lg * 4;
        int bb = gr0 >> 11, t0 = gr0 & (T_LEN - 1);
        half4 o;
        #pragma unroll
        for (int i = 0; i < 4; ++i) o[i] = (_Float16)acc[mi][ni][i];
        *(half4*)&(((_Float16*)outv)[((size_t)bb * C_DIM + gc) * T_LEN + t0]) = o;
      }
    return;
  }

  float bvs[4];
  #pragma unroll
  for (int ni = 0; ni < 4; ++ni) {
    int gc = bn * 256 + wc * 64 + ni * 16 + lr;
    bvs[ni] = bias ? bias[gc & (C_DIM - 1)] : 0.0f;
  }
  #pragma unroll
  for (int mi = 0; mi < 8; ++mi)
    #pragma unroll
    for (int ni = 0; ni < 4; ++ni) {
      int gc = bn * 256 + wc * 64 + ni * 16 + lr;
      #pragma unroll
      for (int i = 0; i < 4; ++i) {
        int gr = bm * 256 + wr * 128 + mi * 16 + lg * 4 + i;
        float v = acc[mi][ni][i] + bvs[ni];
        long long idx = (long long)gr * N + gc;
        if constexpr (EPI == 1) ((float*)outv)[idx] = v;
        else                    ((_Float16*)outv)[idx] = (_Float16)v;
      }
    }
}

// ---------------------------------------------------------------- aggregation (+reference's reshape)
__global__ __launch_bounds__(256) void aggregate_kernel(
    const _Float16* __restrict__ V, const float* __restrict__ wgt,
    const int* __restrict__ dly, _Float16* __restrict__ V2) {
  int b = blockIdx.x & 7;                         // batch pinned to XCD
  int g = (blockIdx.x >> 3) * 256 + threadIdx.x;  // 0 .. T*C/8-1
  int c8 = g & 127;
  int tp = g >> 7;
  int h = tp >> 7, lhi = tp & 127;
  int cp = c8 << 3;
  int e0 = cp & 63, lo = cp >> 6;
  int l = lhi * 16 + lo;
  int ch = h * 64 + e0;
  float acc[8];
  #pragma unroll
  for (int j = 0; j < 8; ++j) acc[j] = 0.0f;
  const long long vbase = (long long)b * T_LEN * C_DIM;
  for (int k = 0; k < TOPK; ++k) {
    float w = wgt[b * TOPK + k];
    int d = dly[b * TOPK + k];
    int ts = (l + d) & (T_LEN - 1);
    half8 vv = *(const half8*)(V + vbase + (long long)ts * C_DIM + ch);
    #pragma unroll
    for (int j = 0; j < 8; ++j) acc[j] += w * (float)vv[j];
  }
  half8 o;
  #pragma unroll
  for (int j = 0; j < 8; ++j) o[j] = (_Float16)acc[j];
  __builtin_nontemporal_store(o, (half8*)(V2 + vbase + (long long)tp * C_DIM + cp));
}

// ---------------------------------------------------------------- launcher
extern "C" void kernel_launch(void* const* d_in, const int* in_sizes, int n_in,
                              void* d_out, int out_size, void* d_ws, size_t ws_size,
                              hipStream_t stream) {
  const float* x  = (const float*)d_in[0];
  const float* Wq = (const float*)d_in[1];
  const float* Wk = (const float*)d_in[3];
  const float* Wv = (const float*)d_in[5];
  const float* bv = (const float*)d_in[6];
  const float* Wp = (const float*)d_in[7];
  const float* bp = (const float*)d_in[8];
  // bq/bk provably irrelevant (constant shift of corr; top-k order & softmax shift-invariant)

  // corr path: Q.K^T == X (Wq Wk^T) X^T; corr[l] = sum_c circcorr(XM_c, x_c)[l]
  //            via per-channel FFT cross-spectrum.
  // ws: [0,32M) XMt -> V2 after fft   [32,64M) V -> Wpt after agg   tail: wgt, dly
  // d_out: [0,32M) xh -> spec+twg -> final out
  //        [32,64M) Wqh/Wkh/Wvt/Mt2 (dead after dual GEMM) -> Xt (32M)
  const size_t SZ_H = (size_t)B_DIM * T_LEN * C_DIM * 2;   // 32 MiB
  const size_t NEEDED = 2 * SZ_H + 65536 + 8192;
  if (ws_size < NEEDED) return;

  char* ws = (char*)d_ws;
  _Float16* XMt = (_Float16*)ws;
  _Float16* V   = (_Float16*)(ws + SZ_H);
  float* wgt   = (float*)(ws + 2 * SZ_H + 65536);
  int*   dly   = (int*)(ws + 2 * SZ_H + 65536 + 4096);
  _Float16* V2  = (_Float16*)ws;             // after fft_corr (XMt dead)
  _Float16* Wpt = (_Float16*)(ws + SZ_H);    // after agg (V dead), 2 MiB

  char* dob = (char*)d_out;
  _Float16* xh  = (_Float16*)dob;
  float*    spec = (float*)dob;                        // after xh dead: 66 KiB
  float*    twg  = (float*)(dob + 131072);             // 8 KiB
  _Float16* Wqh = (_Float16*)(dob + 32 * 1048576);
  _Float16* Wkh = (_Float16*)(dob + 34 * 1048576);
  _Float16* Wvt = (_Float16*)(dob + 36 * 1048576);
  _Float16* Mt2 = (_Float16*)(dob + 38 * 1048576);
  _Float16* Xt  = (_Float16*)(dob + 32 * 1048576);     // after weights dead: 32 MiB

  const int M = B_DIM * T_LEN;  // 16384

  cvt_f16_kernel<<<(M * C_DIM / 8) / 256, 256, 0, stream>>>(x, xh, M * C_DIM / 8);
  cvt_f16_kernel<<<(C_DIM * C_DIM / 8) / 256, 256, 0, stream>>>(Wq, Wqh, C_DIM * C_DIM / 8);
  cvt_f16_kernel<<<(C_DIM * C_DIM / 8) / 256, 256, 0, stream>>>(Wk, Wkh, C_DIM * C_DIM / 8);

  dim3 tgrid(16, 16, 1);
  wt3_kernel<<<tgrid, 256, 0, stream>>>(Wv, Wv, Wv, Wvt, Wvt, Wvt);   // z=0 slice only

  // Mt2[m,n] = sum_o Wk[m,o] * Wq[n,o]  (small: keep 128^2 kernel)
  dim3 mgrid(C_DIM / 128, C_DIM / 128, 1);
  gemm128_kernel<<<mgrid, 256, 0, stream>>>(Wkh, Wqh, Mt2, C_DIM, C_DIM);

  // z=0: XMt[b][c][t] = sum_a x[t,a]*Mt2[c,a] (transposed epi); z=1: V = xh@Wvt + bv
  dim3 pgrid2(M / 256, C_DIM / 256, 2);       // (64, 4, 2)
  gemm256_kernel<2><<<pgrid2, 512, 0, stream>>>(xh, Mt2, nullptr, XMt, C_DIM, C_DIM,
                                                Wvt, bv, V);

  dim3 trgrid(T_LEN / 64, C_DIM / 64, B_DIM); // (32, 16, 8)
  tr16_kernel<<<trgrid, 256, 0, stream>>>(xh, Xt);     // xh dead after (weights dead too)

  init_kernel<<<(B_DIM * SPEC_ST + 255) / 256, 256, 0, stream>>>(spec, B_DIM * SPEC_ST, twg);

  fft_corr_kernel<<<B_DIM * (C_DIM / CG), 256, 0, stream>>>(XMt, Xt, twg, spec);
  ifft_topk_kernel<<<B_DIM, 256, 0, stream>>>(spec, twg, wgt, dly);

  aggregate_kernel<<<(T_LEN * C_DIM / 8 / 256) * B_DIM, 256, 0, stream>>>(V, wgt, dly, V2);

  wt3_kernel<<<tgrid, 256, 0, stream>>>(Wp, Wp, Wp, Wpt, Wpt, Wpt);  // z=0 slice only

  // out = V2 @ Wpt + bp -> d_out f32 (spec/twg/Xt dead)
  dim3 pgrid(M / 256, C_DIM / 256, 1);        // (64, 4)
  gemm256_kernel<1><<<pgrid, 512, 0, stream>>>(V2, Wpt, bp, d_out, C_DIM, C_DIM,
                                               nullptr, nullptr, nullptr);
}